// Round 1
// baseline (724.129 us; speedup 1.0000x reference)
//
#include <hip/hip_runtime.h>
#include <math.h>

// Problem constants (from reference): V=50000, E=128, D=256, L=400, B=64
#define BB 64
#define DD 256
#define LL 400
#define VV 50000
#define EE 128

__device__ __forceinline__ float sigmoidf_(float x){ return 1.0f/(1.0f+expf(-x)); }

// ---------------- K1: x = combine@lin_w.T+b ; h,c = relu(reduce) or passthrough ---
// grid: D blocks, B threads. d = blockIdx (wave-uniform -> scalar weight loads)
__global__ void k_pre(const int* __restrict__ inp, const float* __restrict__ hh,
                      const float* __restrict__ hc, const float* __restrict__ prev,
                      const float* __restrict__ emb_w, const float* __restrict__ lin_w,
                      const float* __restrict__ lin_b, const float* __restrict__ rhw,
                      const float* __restrict__ rhb, const float* __restrict__ rcw,
                      const float* __restrict__ rcb, const int* __restrict__ step_p,
                      float* __restrict__ X, float* __restrict__ H, float* __restrict__ C)
{
    const int d = blockIdx.x;
    const int b = threadIdx.x;
    const int KX = EE + 2*DD; // 640
    const float* lw = lin_w + (size_t)d*KX;
    const float* er = emb_w + (size_t)inp[b]*EE;
    float acc = lin_b[d];
    #pragma unroll 4
    for (int e=0;e<EE;e++) acc += er[e]*lw[e];
    const float* pv = prev + (size_t)b*2*DD;
    #pragma unroll 4
    for (int j=0;j<2*DD;j++) acc += pv[j]*lw[EE+j];
    X[b*DD+d] = acc;

    if (*step_p == 0){
        const float* rh = rhw + (size_t)d*2*DD;
        const float* rc = rcw + (size_t)d*2*DD;
        float ah = rhb[d], ac = rcb[d];
        #pragma unroll 4
        for (int j=0;j<DD;j++){
            ah += hh[b*DD+j]*rh[j] + hh[(size_t)BB*DD + b*DD + j]*rh[DD+j];
            ac += hc[b*DD+j]*rc[j] + hc[(size_t)BB*DD + b*DD + j]*rc[DD+j];
        }
        H[b*DD+d] = ah>0.f?ah:0.f;
        C[b*DD+d] = ac>0.f?ac:0.f;
    } else {
        H[b*DD+d] = hh[b*DD+d];
        C[b*DD+d] = hc[b*DD+d];
    }
}

// ---------------- K2: gates = x@w_ih.T + b_ih + h@w_hh.T + b_hh --------------------
// grid: 4D blocks, B threads
__global__ void k_gates(const float* __restrict__ X, const float* __restrict__ H,
                        const float* __restrict__ w_ih, const float* __restrict__ w_hh,
                        const float* __restrict__ b_ih, const float* __restrict__ b_hh,
                        float* __restrict__ G)
{
    const int g = blockIdx.x;
    const int b = threadIdx.x;
    const float* wi = w_ih + (size_t)g*DD;
    const float* wh = w_hh + (size_t)g*DD;
    float acc = b_ih[g] + b_hh[g];
    #pragma unroll 4
    for (int k=0;k<DD;k++) acc += X[b*DD+k]*wi[k] + H[b*DD+k]*wh[k];
    G[b*4*DD+g] = acc;
}

// ---------------- K3: LSTM elementwise ---------------------------------------------
__global__ void k_lstm(const float* __restrict__ G, const float* __restrict__ C,
                       float* __restrict__ hout, float* __restrict__ cout)
{
    int idx = blockIdx.x*blockDim.x + threadIdx.x;
    if (idx >= BB*DD) return;
    int b = idx / DD, d = idx % DD;
    const float* g = G + (size_t)b*4*DD;
    float i = sigmoidf_(g[d]);
    float f = sigmoidf_(g[DD+d]);
    float gg = tanhf(g[2*DD+d]);
    float o = sigmoidf_(g[3*DD+d]);
    float cn = f*C[idx] + i*gg;
    float hn = o*tanhf(cn);
    cout[idx] = cn;
    hout[idx] = hn;
}

// ---------------- K4: Qs = tanh([h,c]@wq_w.T + wq_b) / sqrt(D) ---------------------
// grid: D blocks, B threads
__global__ void k_q(const float* __restrict__ hout, const float* __restrict__ cout,
                    const float* __restrict__ wq_w, const float* __restrict__ wq_b,
                    float* __restrict__ Qs)
{
    const int d = blockIdx.x;
    const int b = threadIdx.x;
    const float* w = wq_w + (size_t)d*2*DD;
    float acc = wq_b[d];
    #pragma unroll 4
    for (int j=0;j<DD;j++) acc += hout[b*DD+j]*w[j] + cout[b*DD+j]*w[DD+j];
    Qs[b*DD+d] = tanhf(acc) * 0.0625f; // 1/sqrt(256)
}

// ---------------- K5: fused K-projection GEMM + score ------------------------------
// score[b,l] = sum_d Qs[b,d] * tanh( (enc[b,l,:]+cov*cov_w+cov_b) . wk_w[d,:] + wk_b[d] )
// tile: 64 l-rows x 256 d-cols, K=512 in panels of 32. 256 threads, 8x8 micro-tiles.
#define TL 64
#define KT 32
__global__ __launch_bounds__(256) void k_score(
    const float* __restrict__ enc, const float* __restrict__ cov,
    const float* __restrict__ cov_w, const float* __restrict__ cov_b,
    const float* __restrict__ wk_w, const float* __restrict__ wk_b,
    const float* __restrict__ Qs, const float* __restrict__ pmask,
    float* __restrict__ score)
{
    const int b  = blockIdx.y;
    const int l0 = blockIdx.x * TL;
    const int tid = threadIdx.x;
    const int tr = tid >> 5;   // 0..7  -> rows tr + 8*r
    const int tc = tid & 31;   // 0..31 -> cols tc + 32*c
    const int K = 2*DD; // 512

    __shared__ float As[TL][KT+1];
    __shared__ float Bs[DD][KT+1];
    __shared__ float Red[TL][33];

    float acc[8][8];
    #pragma unroll
    for (int r=0;r<8;r++)
        #pragma unroll
        for (int c=0;c<8;c++) acc[r][c]=0.f;

    for (int k0=0;k0<K;k0+=KT){
        // A: 64 rows x 32 k  (word_feature slice)
        #pragma unroll
        for (int i=0;i<(TL*KT)/256;i++){
            int m = i*256 + tid;
            int row = m >> 5, j = m & 31;
            int l = l0 + row;
            float v = 0.f;
            if (l < LL){
                int jj = k0 + j;
                v = enc[((size_t)(b*LL + l))*K + jj] + cov[b*LL+l]*cov_w[jj] + cov_b[jj];
            }
            As[row][j] = v;
        }
        // B: 256 d-rows x 32 k  (wk_w slice, row-major)
        #pragma unroll
        for (int i=0;i<(DD*KT)/256;i++){
            int m = i*256 + tid;
            int d = m >> 5, j = m & 31;
            Bs[d][j] = wk_w[(size_t)d*K + k0 + j];
        }
        __syncthreads();
        #pragma unroll
        for (int k=0;k<KT;k++){
            float a[8], bv[8];
            #pragma unroll
            for (int r=0;r<8;r++) a[r] = As[tr + 8*r][k];
            #pragma unroll
            for (int c=0;c<8;c++) bv[c] = Bs[tc + 32*c][k];
            #pragma unroll
            for (int r=0;r<8;r++)
                #pragma unroll
                for (int c=0;c<8;c++) acc[r][c] += a[r]*bv[c];
        }
        __syncthreads();
    }

    // epilogue: tanh + dot with Qs, reduce over cols
    float part[8];
    #pragma unroll
    for (int r=0;r<8;r++) part[r]=0.f;
    #pragma unroll
    for (int c=0;c<8;c++){
        int d = tc + 32*c;
        float q  = Qs[b*DD + d];
        float kb = wk_b[d];
        #pragma unroll
        for (int r=0;r<8;r++) part[r] += q * tanhf(acc[r][c] + kb);
    }
    #pragma unroll
    for (int r=0;r<8;r++) Red[tr + 8*r][tc] = part[r];
    __syncthreads();
    if (tid < TL){
        int l = l0 + tid;
        if (l < LL){
            float s = 0.f;
            #pragma unroll
            for (int t=0;t<32;t++) s += Red[tid][t];
            score[b*LL + l] = (pmask[b*LL+l] > 0.f) ? s : -1e18f;
        }
    }
}

// ---------------- K6: softmax over L + coverage copy -------------------------------
__global__ void k_softmax_l(const float* __restrict__ score, const float* __restrict__ cov_in,
                            float* __restrict__ attn_out, float* __restrict__ cov_out)
{
    const int b = blockIdx.x;
    const int tid = threadIdx.x; // 256
    __shared__ float red[256];
    float m = -INFINITY;
    for (int l=tid;l<LL;l+=256) m = fmaxf(m, score[b*LL+l]);
    red[tid]=m; __syncthreads();
    for (int s=128;s>0;s>>=1){ if(tid<s) red[tid]=fmaxf(red[tid],red[tid+s]); __syncthreads(); }
    m = red[0]; __syncthreads();
    float sum=0.f;
    for (int l=tid;l<LL;l+=256) sum += expf(score[b*LL+l]-m);
    red[tid]=sum; __syncthreads();
    for (int s=128;s>0;s>>=1){ if(tid<s) red[tid]+=red[tid+s]; __syncthreads(); }
    float inv = 1.0f/red[0];
    for (int l=tid;l<LL;l+=256){
        attn_out[b*LL+l] = expf(score[b*LL+l]-m)*inv;
        cov_out[b*LL+l]  = cov_in[b*LL+l];
    }
}

// ---------------- K7: weighted context (atomic partials) ---------------------------
// grid (4, B), 512 threads; wc must be zeroed beforehand
__global__ void k_wc(const float* __restrict__ attn, const float* __restrict__ enc,
                     float* __restrict__ wc)
{
    const int b = blockIdx.y, ch = blockIdx.x;
    const int j = threadIdx.x; // 0..511
    const int lc = (LL + 3)/4;
    const int l0 = ch*lc;
    const int l1 = (l0+lc < LL) ? l0+lc : LL;
    float s = 0.f;
    for (int l=l0;l<l1;l++) s += attn[b*LL+l]*enc[((size_t)(b*LL+l))*2*DD + j];
    atomicAdd(&wc[b*2*DD+j], s);
}

// ---------------- K8: pregen + p_gen ------------------------------------------------
// grid B blocks, D threads
__global__ void k_bsmall(const float* __restrict__ X, const float* __restrict__ wc,
                         const float* __restrict__ hout, const float* __restrict__ cout,
                         const float* __restrict__ pre_w, const float* __restrict__ pre_b,
                         const float* __restrict__ pgen_w, const float* __restrict__ pgen_b,
                         float* __restrict__ pregen, float* __restrict__ pgen_out)
{
    const int b = blockIdx.x;
    const int d = threadIdx.x; // 0..255
    // pregen = owc @ pre_w.T + pre_b ; owc = [wc(512), h_new(256)]
    const float* w = pre_w + (size_t)d*3*DD;
    float acc = pre_b[d];
    #pragma unroll 4
    for (int j=0;j<2*DD;j++) acc += wc[b*2*DD+j]*w[j];
    #pragma unroll 4
    for (int j=0;j<DD;j++)   acc += hout[b*DD+j]*w[2*DD+j];
    pregen[b*DD+d] = acc;

    // p_gen = sigmoid([x, wc, h, c] . pgen_w + pgen_b), dim 5D=1280
    float p = 0.f;
    for (int j=d;j<5*DD;j+=DD){
        float z;
        if      (j < DD)     z = X[b*DD + j];
        else if (j < 3*DD)   z = wc[b*2*DD + j - DD];
        else if (j < 4*DD)   z = hout[b*DD + j - 3*DD];
        else                 z = cout[b*DD + j - 4*DD];
        p += z * pgen_w[j];
    }
    __shared__ float red[256];
    red[d] = p; __syncthreads();
    for (int s=128;s>0;s>>=1){ if(d<s) red[d]+=red[d+s]; __syncthreads(); }
    if (d==0) pgen_out[b] = sigmoidf_(red[0] + pgen_b[0]);
}

// ---------------- K9: gen logits into final region ---------------------------------
// thread per v, acc[64] over batch; gen_w streamed exactly once
__global__ __launch_bounds__(256) void k_gen(const float* __restrict__ pregen,
                                             const float* __restrict__ gen_w,
                                             const float* __restrict__ gen_b,
                                             float* __restrict__ logits, int W)
{
    const int v = blockIdx.x*256 + threadIdx.x;
    if (v >= VV) return;
    float acc[BB];
    #pragma unroll
    for (int b=0;b<BB;b++) acc[b]=0.f;
    const float4* g4 = (const float4*)(gen_w + (size_t)v*DD);
    for (int k4=0;k4<DD/4;k4++){
        float4 gv = g4[k4];
        #pragma unroll
        for (int b=0;b<BB;b++){
            const float4 pv = ((const float4*)(pregen + b*DD))[k4];
            acc[b] += gv.x*pv.x + gv.y*pv.y + gv.z*pv.z + gv.w*pv.w;
        }
    }
    float gb = gen_b[v];
    #pragma unroll
    for (int b=0;b<BB;b++) logits[(size_t)b*W + v] = acc[b] + gb;
}

// ---------------- K10: vocab softmax stats -----------------------------------------
__global__ void k_vsoftmax(const float* __restrict__ logits, float* __restrict__ Ms,
                           float* __restrict__ Ss, int W)
{
    const int b = blockIdx.x;
    const int tid = threadIdx.x; // 1024
    __shared__ float red[1024];
    const float* row = logits + (size_t)b*W;
    float m = -INFINITY;
    for (int v=tid;v<VV;v+=1024) m = fmaxf(m, row[v]);
    red[tid]=m; __syncthreads();
    for (int s=512;s>0;s>>=1){ if(tid<s) red[tid]=fmaxf(red[tid],red[tid+s]); __syncthreads(); }
    m = red[0]; __syncthreads();
    float sum = 0.f;
    for (int v=tid;v<VV;v+=1024) sum += expf(row[v]-m);
    red[tid]=sum; __syncthreads();
    for (int s=512;s>0;s>>=1){ if(tid<s) red[tid]+=red[tid+s]; __syncthreads(); }
    if (tid==0){ Ms[b]=m; Ss[b]=red[0]; }
}

// ---------------- K11: normalize in place, zero ext region -------------------------
__global__ void k_final(float* __restrict__ out, const float* __restrict__ Ms,
                        const float* __restrict__ Ss, const float* __restrict__ pgen, int W)
{
    size_t idx = (size_t)blockIdx.x*blockDim.x + threadIdx.x;
    if (idx >= (size_t)BB*W) return;
    int b = (int)(idx / W);
    int v = (int)(idx % W);
    float* row = out + (size_t)b*W;
    if (v < VV) row[v] = pgen[b] * expf(row[v]-Ms[b]) / Ss[b];
    else        row[v] = 0.f;
}

// ---------------- K12: scatter-add copy distribution -------------------------------
__global__ void k_scatter(float* __restrict__ out, const int* __restrict__ ext,
                          const float* __restrict__ attn, const float* __restrict__ pgen, int W)
{
    int idx = blockIdx.x*blockDim.x + threadIdx.x;
    if (idx >= BB*LL) return;
    int b = idx / LL;
    atomicAdd(out + (size_t)b*W + ext[idx], (1.0f - pgen[b]) * attn[idx]);
}

extern "C" void kernel_launch(void* const* d_in, const int* in_sizes, int n_in,
                              void* d_out, int out_size, void* d_ws, size_t ws_size,
                              hipStream_t stream)
{
    const int*   inp     = (const int*)  d_in[0];
    const float* hh      = (const float*)d_in[1];
    const float* hc      = (const float*)d_in[2];
    const float* enc     = (const float*)d_in[3];
    const float* prev    = (const float*)d_in[4];
    const int*   ext     = (const int*)  d_in[5];
    const float* cov     = (const float*)d_in[6];
    const float* pmask   = (const float*)d_in[7];
    const int*   step_p  = (const int*)  d_in[9];
    const float* emb_w   = (const float*)d_in[10];
    const float* lin_w   = (const float*)d_in[11];
    const float* lin_b   = (const float*)d_in[12];
    const float* w_ih    = (const float*)d_in[13];
    const float* w_hh    = (const float*)d_in[14];
    const float* b_ih    = (const float*)d_in[15];
    const float* b_hh    = (const float*)d_in[16];
    const float* rhw     = (const float*)d_in[17];
    const float* rhb     = (const float*)d_in[18];
    const float* rcw     = (const float*)d_in[19];
    const float* rcb     = (const float*)d_in[20];
    const float* wq_w    = (const float*)d_in[21];
    const float* wq_b    = (const float*)d_in[22];
    const float* cov_w   = (const float*)d_in[23];
    const float* cov_b   = (const float*)d_in[24];
    const float* wk_w    = (const float*)d_in[25];
    const float* wk_b    = (const float*)d_in[26];
    const float* pre_w   = (const float*)d_in[27];
    const float* pre_b   = (const float*)d_in[28];
    const float* gen_w   = (const float*)d_in[29];
    const float* gen_b   = (const float*)d_in[30];
    const float* pgen_w  = (const float*)d_in[31];
    const float* pgen_b  = (const float*)d_in[32];

    // output layout (flat, return order)
    const int W = out_size / BB - 4*DD - 2*LL - 1;  // V + ex_size = 50200
    float* out     = (float*)d_out;
    float* o_final = out;
    float* o_h     = out + (size_t)BB*W;
    float* o_c     = o_h + BB*DD;
    float* o_wc    = o_c + BB*DD;
    float* o_attn  = o_wc + BB*2*DD;
    float* o_cov   = o_attn + BB*LL;
    float* o_pgen  = o_cov + BB*LL;

    // workspace layout
    float* W_x      = (float*)d_ws;          // B*D
    float* W_h      = W_x + BB*DD;           // B*D
    float* W_c      = W_h + BB*DD;           // B*D
    float* W_gates  = W_c + BB*DD;           // B*4D
    float* W_q      = W_gates + BB*4*DD;     // B*D
    float* W_score  = W_q + BB*DD;           // B*L
    float* W_pregen = W_score + BB*LL;       // B*D
    float* W_m      = W_pregen + BB*DD;      // B
    float* W_s      = W_m + BB;              // B

    hipMemsetAsync(o_wc, 0, (size_t)BB*2*DD*sizeof(float), stream);

    k_pre<<<DD, BB, 0, stream>>>(inp, hh, hc, prev, emb_w, lin_w, lin_b,
                                 rhw, rhb, rcw, rcb, step_p, W_x, W_h, W_c);
    k_gates<<<4*DD, BB, 0, stream>>>(W_x, W_h, w_ih, w_hh, b_ih, b_hh, W_gates);
    k_lstm<<<(BB*DD+255)/256, 256, 0, stream>>>(W_gates, W_c, o_h, o_c);
    k_q<<<DD, BB, 0, stream>>>(o_h, o_c, wq_w, wq_b, W_q);
    k_score<<<dim3((LL+TL-1)/TL, BB), 256, 0, stream>>>(enc, cov, cov_w, cov_b,
                                                        wk_w, wk_b, W_q, pmask, W_score);
    k_softmax_l<<<BB, 256, 0, stream>>>(W_score, cov, o_attn, o_cov);
    k_wc<<<dim3(4, BB), 2*DD, 0, stream>>>(o_attn, enc, o_wc);
    k_bsmall<<<BB, DD, 0, stream>>>(W_x, o_wc, o_h, o_c, pre_w, pre_b,
                                    pgen_w, pgen_b, W_pregen, o_pgen);
    k_gen<<<(VV+255)/256, 256, 0, stream>>>(W_pregen, gen_w, gen_b, o_final, W);
    k_vsoftmax<<<BB, 1024, 0, stream>>>(o_final, W_m, W_s, W);
    k_final<<<(int)(((size_t)BB*W+255)/256), 256, 0, stream>>>(o_final, W_m, W_s, o_pgen, W);
    k_scatter<<<(BB*LL+255)/256, 256, 0, stream>>>(o_final, ext, o_attn, o_pgen, W);
}

// Round 2
// 278.229 us; speedup vs baseline: 2.6026x; 2.6026x over previous
//
#include <hip/hip_runtime.h>
#include <math.h>

// V=50000, E=128, D=256, L=400, B=64
#define BB 64
#define DD 256
#define LL 400
#define VV 50000
#define EE 128

typedef __attribute__((ext_vector_type(8))) short short8v;
typedef __attribute__((ext_vector_type(4))) float f32x4;

__device__ __forceinline__ float sigmoidf_(float x){ return 1.0f/(1.0f+expf(-x)); }

// fp32 -> bf16 bits, round-to-nearest-even
__device__ __forceinline__ short f2bf(float f){
    unsigned u = __builtin_bit_cast(unsigned, f);
    u += 0x7fffu + ((u>>16)&1u);
    return (short)(u>>16);
}

// generic dot: per-lane weight row (vectorized float4) x broadcast vector
__device__ __forceinline__ float dotg(const float* __restrict__ w, const float* __restrict__ s, int n){
    const float4* w4 = (const float4*)w;
    float acc = 0.f;
    #pragma unroll 4
    for (int k=0;k<n/4;k++){
        float4 v = w4[k];
        acc += v.x*s[4*k] + v.y*s[4*k+1] + v.z*s[4*k+2] + v.w*s[4*k+3];
    }
    return acc;
}

// ---------------- prep: wk_w -> bf16, u = wk_w@cov_w, v2 = wk_w@cov_b + wk_b --------
// grid 256 blocks x 64 threads (1 wave)
__global__ void k_prep(const float* __restrict__ wk_w, const float* __restrict__ wk_b,
                       const float* __restrict__ cov_w, const float* __restrict__ cov_b,
                       short* __restrict__ Wb, float* __restrict__ u, float* __restrict__ v2)
{
    const int d = blockIdx.x, t = threadIdx.x;
    const float* row = wk_w + (size_t)d*2*DD;
    float su=0.f, sv=0.f;
    for (int j=t;j<2*DD;j+=64){
        float w = row[j];
        Wb[(size_t)d*2*DD + j] = f2bf(w);
        su += w*cov_w[j];
        sv += w*cov_b[j];
    }
    for (int o=32;o;o>>=1){ su += __shfl_down(su,o); sv += __shfl_down(sv,o); }
    if (t==0){ u[d]=su; v2[d]=sv + wk_b[d]; }
}

// ---------------- front: x, (h,c reduce), gates, LSTM, Q — one block per batch -----
__global__ __launch_bounds__(256) void k_front(
    const int* __restrict__ inp, const float* __restrict__ hh, const float* __restrict__ hc,
    const float* __restrict__ prev, const float* __restrict__ emb_w,
    const float* __restrict__ lin_w, const float* __restrict__ lin_b,
    const float* __restrict__ rhw, const float* __restrict__ rhb,
    const float* __restrict__ rcw, const float* __restrict__ rcb,
    const int* __restrict__ step_p,
    const float* __restrict__ w_ih, const float* __restrict__ w_hh,
    const float* __restrict__ b_ih, const float* __restrict__ b_hh,
    const float* __restrict__ wq_w, const float* __restrict__ wq_b,
    float* __restrict__ o_h, float* __restrict__ o_c,
    float* __restrict__ Qs, float* __restrict__ Xout)
{
    const int b = blockIdx.x, d = threadIdx.x;
    __shared__ float comb[EE+2*DD];
    __shared__ float xs[DD], hs[DD], cs[DD], hn[DD], cn[DD];

    const float* er = emb_w + (size_t)inp[b]*EE;
    for (int j=d;j<EE;j+=DD)    comb[j]     = er[j];
    for (int j=d;j<2*DD;j+=DD)  comb[EE+j]  = prev[(size_t)b*2*DD + j];
    __syncthreads();

    // x = combine @ lin_w.T + lin_b
    {
        float acc = lin_b[d] + dotg(lin_w + (size_t)d*(EE+2*DD), comb, EE+2*DD);
        xs[d] = acc; Xout[b*DD+d] = acc;
    }
    // h, c
    float h, c;
    if (*step_p == 0){
        const float* h0 = hh + (size_t)b*DD; const float* h1 = hh + (size_t)BB*DD + (size_t)b*DD;
        const float* c0 = hc + (size_t)b*DD; const float* c1 = hc + (size_t)BB*DD + (size_t)b*DD;
        float ah = rhb[d] + dotg(rhw + (size_t)d*2*DD, h0, DD) + dotg(rhw + (size_t)d*2*DD + DD, h1, DD);
        float ac = rcb[d] + dotg(rcw + (size_t)d*2*DD, c0, DD) + dotg(rcw + (size_t)d*2*DD + DD, c1, DD);
        h = ah>0.f?ah:0.f;  c = ac>0.f?ac:0.f;
    } else {
        h = hh[(size_t)b*DD + d];  c = hc[(size_t)b*DD + d];
    }
    hs[d] = h; cs[d] = c;
    __syncthreads();

    // gates
    float g[4];
    #pragma unroll
    for (int gi=0; gi<4; gi++){
        const int gr = gi*DD + d;
        g[gi] = b_ih[gr] + b_hh[gr]
              + dotg(w_ih + (size_t)gr*DD, xs, DD)
              + dotg(w_hh + (size_t)gr*DD, hs, DD);
    }
    float iv = sigmoidf_(g[0]), fv = sigmoidf_(g[1]);
    float gv = tanhf(g[2]),     ov = sigmoidf_(g[3]);
    float cnew = fv*c + iv*gv;
    float hnew = ov*tanhf(cnew);
    o_h[(size_t)b*DD + d] = hnew;
    o_c[(size_t)b*DD + d] = cnew;
    hn[d] = hnew; cn[d] = cnew;
    __syncthreads();

    // Q
    float q = wq_b[d] + dotg(wq_w + (size_t)d*2*DD, hn, DD) + dotg(wq_w + (size_t)d*2*DD + DD, cn, DD);
    Qs[b*DD + d] = tanhf(q) * 0.0625f; // / sqrt(256)
}

// ---------------- score: MFMA bf16, fused tanh epilogue + row-reduce ----------------
// score[b,l] = sum_d Qs[b,d] * tanh( (enc@wk^T)[l,d] + cov[b,l]*u[d] + v2[d] )
// block: batch b, 64 l-rows x 256 d-cols; 4 waves (wave w -> cols 64w..64w+63)
__global__ __launch_bounds__(256) void k_score_mfma(
    const float* __restrict__ enc, const short* __restrict__ Wb,
    const float* __restrict__ u, const float* __restrict__ v2,
    const float* __restrict__ Qs, const float* __restrict__ cov,
    const float* __restrict__ pmask, float* __restrict__ score)
{
    const int b  = blockIdx.y;
    const int l0 = blockIdx.x * 64;
    const int tid = threadIdx.x;
    const int wave = tid >> 6, lane = tid & 63;
    const int qw = lane >> 4, lr = lane & 15;

    __shared__ short Al[64*64];      // 8 KB, XOR-swizzled 16B chunks
    __shared__ short Bl[256*64];     // 32 KB
    __shared__ float Red[4][64];

    f32x4 acc[4][4];
    #pragma unroll
    for (int i=0;i<4;i++)
        #pragma unroll
        for (int j=0;j<4;j++) acc[i][j] = f32x4{0.f,0.f,0.f,0.f};

    const int ar  = tid >> 2;          // A row 0..63
    const int asg = (tid & 3) * 16;    // k segment
    const int al  = l0 + ar;
    const int brow0 = tid >> 3, cb = tid & 7;

    for (int k0 = 0; k0 < 512; k0 += 64){
        if (k0) __syncthreads();
        // stage A: enc fp32 -> bf16 (64 rows x 64 k)
        {
            short tmp[16];
            if (al < LL){
                const float4* src = (const float4*)(enc + ((size_t)(b*LL + al))*512 + k0 + asg);
                #pragma unroll
                for (int i=0;i<4;i++){
                    float4 v = src[i];
                    tmp[4*i+0]=f2bf(v.x); tmp[4*i+1]=f2bf(v.y);
                    tmp[4*i+2]=f2bf(v.z); tmp[4*i+3]=f2bf(v.w);
                }
            } else {
                #pragma unroll
                for (int i=0;i<16;i++) tmp[i]=0;
            }
            const int c0 = asg >> 3;
            #pragma unroll
            for (int i=0;i<2;i++){
                int cc = (c0+i) ^ (ar & 7);
                *(short8v*)&Al[ar*64 + cc*8] = *(const short8v*)&tmp[8*i];
            }
        }
        // stage B: Wb bf16 (256 rows x 64 k)
        #pragma unroll
        for (int p=0;p<8;p++){
            int row = brow0 + 32*p;
            short8v w = *(const short8v*)(Wb + (size_t)row*512 + k0 + cb*8);
            *(short8v*)&Bl[row*64 + ((cb ^ (row&7))*8)] = w;
        }
        __syncthreads();

        #pragma unroll
        for (int ks=0; ks<2; ks++){
            const int jc = ks*4 + qw;
            short8v a[4], bb[4];
            #pragma unroll
            for (int rf=0;rf<4;rf++){
                int row = rf*16 + lr;
                a[rf] = *(const short8v*)&Al[row*64 + ((jc ^ (row&7))*8)];
            }
            #pragma unroll
            for (int cf=0;cf<4;cf++){
                int row = wave*64 + cf*16 + lr;
                bb[cf] = *(const short8v*)&Bl[row*64 + ((jc ^ (row&7))*8)];
            }
            #pragma unroll
            for (int rf=0;rf<4;rf++)
                #pragma unroll
                for (int cf=0;cf<4;cf++)
                    acc[rf][cf] = __builtin_amdgcn_mfma_f32_16x16x32_bf16(a[rf], bb[cf], acc[rf][cf], 0,0,0);
        }
    }

    // epilogue: tanh + Qs dot + row reduce
    float qd[4], ud[4], vd[4];
    #pragma unroll
    for (int cf=0;cf<4;cf++){
        int dcol = wave*64 + cf*16 + lr;
        qd[cf] = Qs[b*DD + dcol];
        ud[cf] = u[dcol];
        vd[cf] = v2[dcol];
    }
    #pragma unroll
    for (int rf=0;rf<4;rf++){
        int rbase = l0 + rf*16 + qw*4;
        float cv[4];
        if (rbase < LL){
            float4 c4 = *(const float4*)(cov + (size_t)b*LL + rbase);
            cv[0]=c4.x; cv[1]=c4.y; cv[2]=c4.z; cv[3]=c4.w;
        } else { cv[0]=cv[1]=cv[2]=cv[3]=0.f; }
        #pragma unroll
        for (int r=0;r<4;r++){
            float s = 0.f;
            #pragma unroll
            for (int cf=0;cf<4;cf++)
                s += qd[cf] * tanhf(acc[rf][cf][r] + cv[r]*ud[cf] + vd[cf]);
            s += __shfl_xor(s,1); s += __shfl_xor(s,2);
            s += __shfl_xor(s,4); s += __shfl_xor(s,8);
            if (lr == 0) Red[wave][rf*16 + qw*4 + r] = s;
        }
    }
    __syncthreads();
    if (tid < 64){
        int l = l0 + tid;
        if (l < LL){
            float s = Red[0][tid]+Red[1][tid]+Red[2][tid]+Red[3][tid];
            score[b*LL + l] = (pmask[b*LL+l] > 0.f) ? s : -1e18f;
        }
    }
}

// ---------------- softmax over L + coverage copy ------------------------------------
__global__ void k_softmax_l(const float* __restrict__ score, const float* __restrict__ cov_in,
                            float* __restrict__ attn_out, float* __restrict__ cov_out)
{
    const int b = blockIdx.x;
    const int tid = threadIdx.x; // 256
    __shared__ float red[256];
    float m = -INFINITY;
    for (int l=tid;l<LL;l+=256) m = fmaxf(m, score[b*LL+l]);
    red[tid]=m; __syncthreads();
    for (int s=128;s>0;s>>=1){ if(tid<s) red[tid]=fmaxf(red[tid],red[tid+s]); __syncthreads(); }
    m = red[0]; __syncthreads();
    float sum=0.f;
    for (int l=tid;l<LL;l+=256) sum += expf(score[b*LL+l]-m);
    red[tid]=sum; __syncthreads();
    for (int s=128;s>0;s>>=1){ if(tid<s) red[tid]+=red[tid+s]; __syncthreads(); }
    float inv = 1.0f/red[0];
    for (int l=tid;l<LL;l+=256){
        attn_out[b*LL+l] = expf(score[b*LL+l]-m)*inv;
        cov_out[b*LL+l]  = cov_in[b*LL+l];
    }
}

// ---------------- weighted context --------------------------------------------------
__global__ void k_wc(const float* __restrict__ attn, const float* __restrict__ enc,
                     float* __restrict__ wc)
{
    const int b = blockIdx.y, ch = blockIdx.x;
    const int j = threadIdx.x; // 0..511
    const int lc = (LL + 3)/4;
    const int l0 = ch*lc;
    const int l1 = (l0+lc < LL) ? l0+lc : LL;
    float s = 0.f;
    for (int l=l0;l<l1;l++) s += attn[b*LL+l]*enc[((size_t)(b*LL+l))*2*DD + j];
    atomicAdd(&wc[b*2*DD+j], s);
}

// ---------------- pregen + p_gen -----------------------------------------------------
__global__ void k_bsmall(const float* __restrict__ X, const float* __restrict__ wc,
                         const float* __restrict__ hout, const float* __restrict__ cout,
                         const float* __restrict__ pre_w, const float* __restrict__ pre_b,
                         const float* __restrict__ pgen_w, const float* __restrict__ pgen_b,
                         float* __restrict__ pregen, float* __restrict__ pgen_out)
{
    const int b = blockIdx.x;
    const int d = threadIdx.x; // 0..255
    const float* w = pre_w + (size_t)d*3*DD;
    float acc = pre_b[d];
    #pragma unroll 4
    for (int j=0;j<2*DD;j++) acc += wc[b*2*DD+j]*w[j];
    #pragma unroll 4
    for (int j=0;j<DD;j++)   acc += hout[b*DD+j]*w[2*DD+j];
    pregen[b*DD+d] = acc;

    float p = 0.f;
    for (int j=d;j<5*DD;j+=DD){
        float z;
        if      (j < DD)     z = X[b*DD + j];
        else if (j < 3*DD)   z = wc[b*2*DD + j - DD];
        else if (j < 4*DD)   z = hout[b*DD + j - 3*DD];
        else                 z = cout[b*DD + j - 4*DD];
        p += z * pgen_w[j];
    }
    __shared__ float red[256];
    red[d] = p; __syncthreads();
    for (int s=128;s>0;s>>=1){ if(d<s) red[d]+=red[d+s]; __syncthreads(); }
    if (d==0) pgen_out[b] = sigmoidf_(red[0] + pgen_b[0]);
}

// ---------------- gen logits: MFMA bf16, gen_w converted in-flight -------------------
// M=64 batches x N-tile 128 vocab x K=256; grid 391 blocks
__global__ __launch_bounds__(256) void k_gen_mfma(
    const float* __restrict__ pregen, const float* __restrict__ gen_w,
    const float* __restrict__ gen_b, float* __restrict__ logits, int W)
{
    const int v0 = blockIdx.x * 128;
    const int tid = threadIdx.x;
    const int wave = tid>>6, lane = tid&63, qw = lane>>4, lr = lane&15;

    __shared__ short Al[64*64];     // 8 KB
    __shared__ short Bl[128*64];    // 16 KB

    f32x4 acc[4][2];
    #pragma unroll
    for (int i=0;i<4;i++){ acc[i][0]=f32x4{0.f,0.f,0.f,0.f}; acc[i][1]=f32x4{0.f,0.f,0.f,0.f}; }

    const int ar = tid>>2, asg = (tid&3)*16;
    const int br = tid>>1, kh = (tid&1)*32;
    const int vrow = v0 + br;

    for (int k0=0;k0<256;k0+=64){
        if (k0) __syncthreads();
        // stage A: pregen fp32 -> bf16
        {
            const float4* src = (const float4*)(pregen + ar*DD + k0 + asg);
            short tmp[16];
            #pragma unroll
            for (int i=0;i<4;i++){
                float4 v = src[i];
                tmp[4*i+0]=f2bf(v.x); tmp[4*i+1]=f2bf(v.y);
                tmp[4*i+2]=f2bf(v.z); tmp[4*i+3]=f2bf(v.w);
            }
            const int c0 = asg >> 3;
            #pragma unroll
            for (int i=0;i<2;i++){
                int cc = (c0+i) ^ (ar & 7);
                *(short8v*)&Al[ar*64 + cc*8] = *(const short8v*)&tmp[8*i];
            }
        }
        // stage B: gen_w rows (fp32 -> bf16), 128 rows x 64 k
        {
            short tmp[32];
            if (vrow < VV){
                const float4* src = (const float4*)(gen_w + (size_t)vrow*DD + k0 + kh);
                #pragma unroll
                for (int i=0;i<8;i++){
                    float4 v = src[i];
                    tmp[4*i+0]=f2bf(v.x); tmp[4*i+1]=f2bf(v.y);
                    tmp[4*i+2]=f2bf(v.z); tmp[4*i+3]=f2bf(v.w);
                }
            } else {
                #pragma unroll
                for (int i=0;i<32;i++) tmp[i]=0;
            }
            const int c0 = kh >> 3;
            #pragma unroll
            for (int i=0;i<4;i++){
                int cc = (c0+i) ^ (br & 7);
                *(short8v*)&Bl[br*64 + cc*8] = *(const short8v*)&tmp[8*i];
            }
        }
        __syncthreads();

        #pragma unroll
        for (int ks=0; ks<2; ks++){
            const int jc = ks*4 + qw;
            short8v a[4], bb[2];
            #pragma unroll
            for (int rf=0;rf<4;rf++){
                int row = rf*16 + lr;
                a[rf] = *(const short8v*)&Al[row*64 + ((jc ^ (row&7))*8)];
            }
            #pragma unroll
            for (int cf=0;cf<2;cf++){
                int row = wave*32 + cf*16 + lr;
                bb[cf] = *(const short8v*)&Bl[row*64 + ((jc ^ (row&7))*8)];
            }
            #pragma unroll
            for (int rf=0;rf<4;rf++)
                #pragma unroll
                for (int cf=0;cf<2;cf++)
                    acc[rf][cf] = __builtin_amdgcn_mfma_f32_16x16x32_bf16(a[rf], bb[cf], acc[rf][cf], 0,0,0);
        }
    }

    // epilogue
    #pragma unroll
    for (int cf=0;cf<2;cf++){
        int v = v0 + wave*32 + cf*16 + lr;
        if (v < VV){
            float gb = gen_b[v];
            #pragma unroll
            for (int rf=0;rf<4;rf++){
                #pragma unroll
                for (int r=0;r<4;r++){
                    int bt = rf*16 + qw*4 + r;
                    logits[(size_t)bt*W + v] = acc[rf][cf][r] + gb;
                }
            }
        }
    }
}

// ---------------- vocab softmax stats -----------------------------------------------
__global__ void k_vsoftmax(const float* __restrict__ logits, float* __restrict__ Ms,
                           float* __restrict__ Ss, int W)
{
    const int b = blockIdx.x;
    const int tid = threadIdx.x; // 1024
    __shared__ float red[1024];
    const float* row = logits + (size_t)b*W;
    float m = -INFINITY;
    for (int v=tid;v<VV;v+=1024) m = fmaxf(m, row[v]);
    red[tid]=m; __syncthreads();
    for (int s=512;s>0;s>>=1){ if(tid<s) red[tid]=fmaxf(red[tid],red[tid+s]); __syncthreads(); }
    m = red[0]; __syncthreads();
    float sum = 0.f;
    for (int v=tid;v<VV;v+=1024) sum += expf(row[v]-m);
    red[tid]=sum; __syncthreads();
    for (int s=512;s>0;s>>=1){ if(tid<s) red[tid]+=red[tid+s]; __syncthreads(); }
    if (tid==0){ Ms[b]=m; Ss[b]=red[0]; }
}

// ---------------- normalize + zero ext ----------------------------------------------
__global__ void k_final(float* __restrict__ out, const float* __restrict__ Ms,
                        const float* __restrict__ Ss, const float* __restrict__ pgen, int W)
{
    size_t idx = (size_t)blockIdx.x*blockDim.x + threadIdx.x;
    if (idx >= (size_t)BB*W) return;
    int b = (int)(idx / W);
    int v = (int)(idx % W);
    float* row = out + (size_t)b*W;
    if (v < VV) row[v] = pgen[b] * expf(row[v]-Ms[b]) / Ss[b];
    else        row[v] = 0.f;
}

// ---------------- scatter-add copy dist ----------------------------------------------
__global__ void k_scatter(float* __restrict__ out, const int* __restrict__ ext,
                          const float* __restrict__ attn, const float* __restrict__ pgen, int W)
{
    int idx = blockIdx.x*blockDim.x + threadIdx.x;
    if (idx >= BB*LL) return;
    int b = idx / LL;
    atomicAdd(out + (size_t)b*W + ext[idx], (1.0f - pgen[b]) * attn[idx]);
}

extern "C" void kernel_launch(void* const* d_in, const int* in_sizes, int n_in,
                              void* d_out, int out_size, void* d_ws, size_t ws_size,
                              hipStream_t stream)
{
    const int*   inp     = (const int*)  d_in[0];
    const float* hh      = (const float*)d_in[1];
    const float* hc      = (const float*)d_in[2];
    const float* enc     = (const float*)d_in[3];
    const float* prev    = (const float*)d_in[4];
    const int*   ext     = (const int*)  d_in[5];
    const float* cov     = (const float*)d_in[6];
    const float* pmask   = (const float*)d_in[7];
    const int*   step_p  = (const int*)  d_in[9];
    const float* emb_w   = (const float*)d_in[10];
    const float* lin_w   = (const float*)d_in[11];
    const float* lin_b   = (const float*)d_in[12];
    const float* w_ih    = (const float*)d_in[13];
    const float* w_hh    = (const float*)d_in[14];
    const float* b_ih    = (const float*)d_in[15];
    const float* b_hh    = (const float*)d_in[16];
    const float* rhw     = (const float*)d_in[17];
    const float* rhb     = (const float*)d_in[18];
    const float* rcw     = (const float*)d_in[19];
    const float* rcb     = (const float*)d_in[20];
    const float* wq_w    = (const float*)d_in[21];
    const float* wq_b    = (const float*)d_in[22];
    const float* cov_w   = (const float*)d_in[23];
    const float* cov_b   = (const float*)d_in[24];
    const float* wk_w    = (const float*)d_in[25];
    const float* wk_b    = (const float*)d_in[26];
    const float* pre_w   = (const float*)d_in[27];
    const float* pre_b   = (const float*)d_in[28];
    const float* gen_w   = (const float*)d_in[29];
    const float* gen_b   = (const float*)d_in[30];
    const float* pgen_w  = (const float*)d_in[31];
    const float* pgen_b  = (const float*)d_in[32];

    const int W = out_size / BB - 4*DD - 2*LL - 1;  // V + ex_size = 50200
    float* out     = (float*)d_out;
    float* o_final = out;
    float* o_h     = out + (size_t)BB*W;
    float* o_c     = o_h + BB*DD;
    float* o_wc    = o_c + BB*DD;
    float* o_attn  = o_wc + BB*2*DD;
    float* o_cov   = o_attn + BB*LL;
    float* o_pgen  = o_cov + BB*LL;

    // workspace
    float* W_x      = (float*)d_ws;          // B*D
    float* W_q      = W_x + BB*DD;           // B*D
    float* W_score  = W_q + BB*DD;           // B*L
    float* W_pregen = W_score + BB*LL;       // B*D
    float* W_m      = W_pregen + BB*DD;      // B
    float* W_s      = W_m + BB;              // B
    float* W_u      = W_s + BB;              // D
    float* W_v2     = W_u + DD;              // D
    short* W_wb     = (short*)(W_v2 + DD);   // D * 2D bf16

    hipMemsetAsync(o_wc, 0, (size_t)BB*2*DD*sizeof(float), stream);

    k_prep<<<DD, 64, 0, stream>>>(wk_w, wk_b, cov_w, cov_b, W_wb, W_u, W_v2);
    k_front<<<BB, DD, 0, stream>>>(inp, hh, hc, prev, emb_w, lin_w, lin_b,
                                   rhw, rhb, rcw, rcb, step_p,
                                   w_ih, w_hh, b_ih, b_hh, wq_w, wq_b,
                                   o_h, o_c, W_q, W_x);
    k_score_mfma<<<dim3(7, BB), 256, 0, stream>>>(enc, W_wb, W_u, W_v2, W_q, cov, pmask, W_score);
    k_softmax_l<<<BB, 256, 0, stream>>>(W_score, cov, o_attn, o_cov);
    k_wc<<<dim3(4, BB), 2*DD, 0, stream>>>(o_attn, enc, o_wc);
    k_bsmall<<<BB, DD, 0, stream>>>(W_x, o_wc, o_h, o_c, pre_w, pre_b,
                                    pgen_w, pgen_b, W_pregen, o_pgen);
    k_gen_mfma<<<(VV+127)/128, 256, 0, stream>>>(W_pregen, gen_w, gen_b, o_final, W);
    k_vsoftmax<<<BB, 1024, 0, stream>>>(o_final, W_m, W_s, W);
    k_final<<<(int)(((size_t)BB*W+255)/256), 256, 0, stream>>>(o_final, W_m, W_s, o_pgen, W);
    k_scatter<<<(BB*LL+255)/256, 256, 0, stream>>>(o_final, ext, o_attn, o_pgen, W);
}

// Round 3
// 198.964 us; speedup vs baseline: 3.6395x; 1.3984x over previous
//
#include <hip/hip_runtime.h>
#include <math.h>

// V=50000, E=128, D=256, L=400, B=64
#define BB 64
#define DD 256
#define LL 400
#define VV 50000
#define EE 128

typedef __attribute__((ext_vector_type(8))) short short8v;
typedef __attribute__((ext_vector_type(4))) float f32x4;

__device__ __forceinline__ float sigmoidf_(float x){ return 1.0f/(1.0f+expf(-x)); }

// fp32 -> bf16 bits, round-to-nearest-even
__device__ __forceinline__ short f2bf(float f){
    unsigned u = __builtin_bit_cast(unsigned, f);
    u += 0x7fffu + ((u>>16)&1u);
    return (short)(u>>16);
}

__device__ __forceinline__ float dot4(float4 a, float4 b){
    return a.x*b.x + a.y*b.y + a.z*b.z + a.w*b.w;
}

// ============ FRONT STAGE 1: x, h, c (+ score prep) ================================
// grid (DD, 4) x 256 threads. y=0: x[b,d]; y=1: h; y=2: c; y=3: wk prep row d.
// Pattern: weight row d staged in LDS; 4 waves K-split; lane = batch.
__global__ __launch_bounds__(256) void k_front1(
    const int* __restrict__ inp, const float* __restrict__ hh, const float* __restrict__ hc,
    const float* __restrict__ prev, const float* __restrict__ emb_w,
    const float* __restrict__ lin_w, const float* __restrict__ lin_b,
    const float* __restrict__ rhw, const float* __restrict__ rhb,
    const float* __restrict__ rcw, const float* __restrict__ rcb,
    const int* __restrict__ step_p,
    const float* __restrict__ wk_w, const float* __restrict__ wk_b,
    const float* __restrict__ cov_w, const float* __restrict__ cov_b,
    float* __restrict__ X, float* __restrict__ Wh, float* __restrict__ Wc,
    short* __restrict__ Wb, float* __restrict__ u, float* __restrict__ v2)
{
    const int d = blockIdx.x, y = blockIdx.y, t = threadIdx.x;
    const int b = t & 63, w = t >> 6;
    __shared__ float lw[640];
    __shared__ float red[4][64];

    if (y == 3){
        // prep: wk_w row -> bf16; u[d] = wk_w[d]·cov_w ; v2[d] = wk_w[d]·cov_b + wk_b[d]
        const float* row = wk_w + (size_t)d*512;
        float su=0.f, sv=0.f;
        for (int j=t; j<512; j+=256){
            float wv = row[j];
            Wb[(size_t)d*512 + j] = f2bf(wv);
            su += wv*cov_w[j];
            sv += wv*cov_b[j];
        }
        float* rs = lw;
        float* rv = &red[0][0];
        rs[t]=su; rv[t]=sv; __syncthreads();
        for (int s=128;s>0;s>>=1){ if(t<s){rs[t]+=rs[t+s]; rv[t]+=rv[t+s];} __syncthreads(); }
        if (t==0){ u[d]=rs[0]; v2[d]=rv[0] + wk_b[d]; }
        return;
    }

    if (y == 0){
        // x[b,d] = lin_b[d] + [emb(128), prev(512)] . lin_w[d,:]
        const float4* src4 = (const float4*)(lin_w + (size_t)d*640);
        float4* lw4s = (float4*)lw;
        if (t < 160) lw4s[t] = src4[t];
        __syncthreads();
        const float4* lw4 = (const float4*)lw;
        const float4* er4 = (const float4*)(emb_w + (size_t)inp[b]*EE);
        const float4* pv4 = (const float4*)(prev + (size_t)b*512);
        float acc = 0.f;
        for (int i4=w; i4<32; i4+=4)       acc += dot4(er4[i4],      lw4[i4]);
        for (int i4=32+w; i4<160; i4+=4)   acc += dot4(pv4[i4-32],   lw4[i4]);
        red[w][b] = acc; __syncthreads();
        if (t < 64)
            X[(size_t)t*DD + d] = lin_b[d] + red[0][t]+red[1][t]+red[2][t]+red[3][t];
        return;
    }

    // y==1: h, y==2: c
    const float* src  = (y==1) ? hh  : hc;
    float*       dst  = (y==1) ? Wh  : Wc;
    if (*step_p == 0){
        const float* wrow = ((y==1) ? rhw : rcw) + (size_t)d*512;
        const float  bias = ((y==1) ? rhb : rcb)[d];
        float4* lw4s = (float4*)lw;
        if (t < 128) lw4s[t] = ((const float4*)wrow)[t];
        __syncthreads();
        const float4* lw4 = (const float4*)lw;
        const float4* s0 = (const float4*)(src + (size_t)b*DD);
        const float4* s1 = (const float4*)(src + (size_t)BB*DD + (size_t)b*DD);
        float acc = 0.f;
        for (int i4=w; i4<64; i4+=4)      acc += dot4(s0[i4],    lw4[i4]);
        for (int i4=64+w; i4<128; i4+=4)  acc += dot4(s1[i4-64], lw4[i4]);
        red[w][b] = acc; __syncthreads();
        if (t < 64){
            float a = bias + red[0][t]+red[1][t]+red[2][t]+red[3][t];
            dst[(size_t)t*DD + d] = a>0.f ? a : 0.f;
        }
    } else {
        if (t < 64) dst[(size_t)t*DD + d] = src[(size_t)t*DD + d];
    }
}

// ============ FRONT STAGE 2: gates + LSTM ==========================================
// grid DD blocks x 256 threads. wave = gate gi, lane = batch b.
__global__ __launch_bounds__(256) void k_gl(
    const float* __restrict__ X, const float* __restrict__ Wh, const float* __restrict__ Wc,
    const float* __restrict__ w_ih, const float* __restrict__ w_hh,
    const float* __restrict__ b_ih, const float* __restrict__ b_hh,
    float* __restrict__ o_h, float* __restrict__ o_c)
{
    const int d = blockIdx.x, t = threadIdx.x;
    const int b = t & 63, gi = t >> 6;
    __shared__ float wih[4][256];
    __shared__ float whh[4][256];
    __shared__ float gl[4][64];

    const int gr = gi*DD + d;
    ((float4*)&wih[gi][0])[b] = ((const float4*)(w_ih + (size_t)gr*DD))[b];
    ((float4*)&whh[gi][0])[b] = ((const float4*)(w_hh + (size_t)gr*DD))[b];
    __syncthreads();

    const float4* x4 = (const float4*)(X  + (size_t)b*DD);
    const float4* h4 = (const float4*)(Wh + (size_t)b*DD);
    const float4* wi4 = (const float4*)&wih[gi][0];
    const float4* wh4 = (const float4*)&whh[gi][0];
    float a0=0.f, a1=0.f;
    #pragma unroll 8
    for (int i=0;i<64;i++){
        a0 += dot4(x4[i], wi4[i]);
        a1 += dot4(h4[i], wh4[i]);
    }
    gl[gi][b] = a0 + a1 + b_ih[gr] + b_hh[gr];
    __syncthreads();

    if (t < 64){
        float iv = sigmoidf_(gl[0][t]);
        float fv = sigmoidf_(gl[1][t]);
        float gv = tanhf(gl[2][t]);
        float ov = sigmoidf_(gl[3][t]);
        float cn = fv*Wc[(size_t)t*DD + d] + iv*gv;
        float hn = ov*tanhf(cn);
        o_c[(size_t)t*DD + d] = cn;
        o_h[(size_t)t*DD + d] = hn;
    }
}

// ============ FRONT STAGE 3: Q =====================================================
// grid DD x 256. Qs[b,d] = tanh([h,c].wq_w[d] + wq_b[d]) / 16
__global__ __launch_bounds__(256) void k_q2(
    const float* __restrict__ o_h, const float* __restrict__ o_c,
    const float* __restrict__ wq_w, const float* __restrict__ wq_b,
    float* __restrict__ Qs)
{
    const int d = blockIdx.x, t = threadIdx.x;
    const int b = t & 63, w = t >> 6;
    __shared__ float lw[512];
    __shared__ float red[4][64];
    if (t < 128) ((float4*)lw)[t] = ((const float4*)(wq_w + (size_t)d*512))[t];
    __syncthreads();
    const float4* lw4 = (const float4*)lw;
    const float4* h4 = (const float4*)(o_h + (size_t)b*DD);
    const float4* c4 = (const float4*)(o_c + (size_t)b*DD);
    float acc = 0.f;
    for (int i4=w; i4<64; i4+=4)      acc += dot4(h4[i4],    lw4[i4]);
    for (int i4=64+w; i4<128; i4+=4)  acc += dot4(c4[i4-64], lw4[i4]);
    red[w][b] = acc; __syncthreads();
    if (t < 64)
        Qs[(size_t)t*DD + d] = tanhf(wq_b[d] + red[0][t]+red[1][t]+red[2][t]+red[3][t]) * 0.0625f;
}

// ---------------- score: MFMA bf16, fused tanh epilogue + row-reduce ----------------
__global__ __launch_bounds__(256) void k_score_mfma(
    const float* __restrict__ enc, const short* __restrict__ Wb,
    const float* __restrict__ u, const float* __restrict__ v2,
    const float* __restrict__ Qs, const float* __restrict__ cov,
    const float* __restrict__ pmask, float* __restrict__ score)
{
    const int b  = blockIdx.y;
    const int l0 = blockIdx.x * 64;
    const int tid = threadIdx.x;
    const int wave = tid >> 6, lane = tid & 63;
    const int qw = lane >> 4, lr = lane & 15;

    __shared__ short Al[64*64];
    __shared__ short Bl[256*64];
    __shared__ float Red[4][64];

    f32x4 acc[4][4];
    #pragma unroll
    for (int i=0;i<4;i++)
        #pragma unroll
        for (int j=0;j<4;j++) acc[i][j] = f32x4{0.f,0.f,0.f,0.f};

    const int ar  = tid >> 2;
    const int asg = (tid & 3) * 16;
    const int al  = l0 + ar;
    const int brow0 = tid >> 3, cb = tid & 7;

    for (int k0 = 0; k0 < 512; k0 += 64){
        if (k0) __syncthreads();
        {
            short tmp[16];
            if (al < LL){
                const float4* src = (const float4*)(enc + ((size_t)(b*LL + al))*512 + k0 + asg);
                #pragma unroll
                for (int i=0;i<4;i++){
                    float4 v = src[i];
                    tmp[4*i+0]=f2bf(v.x); tmp[4*i+1]=f2bf(v.y);
                    tmp[4*i+2]=f2bf(v.z); tmp[4*i+3]=f2bf(v.w);
                }
            } else {
                #pragma unroll
                for (int i=0;i<16;i++) tmp[i]=0;
            }
            const int c0 = asg >> 3;
            #pragma unroll
            for (int i=0;i<2;i++){
                int cc = (c0+i) ^ (ar & 7);
                *(short8v*)&Al[ar*64 + cc*8] = *(const short8v*)&tmp[8*i];
            }
        }
        #pragma unroll
        for (int p=0;p<8;p++){
            int row = brow0 + 32*p;
            short8v wv = *(const short8v*)(Wb + (size_t)row*512 + k0 + cb*8);
            *(short8v*)&Bl[row*64 + ((cb ^ (row&7))*8)] = wv;
        }
        __syncthreads();

        #pragma unroll
        for (int ks=0; ks<2; ks++){
            const int jc = ks*4 + qw;
            short8v a[4], bb[4];
            #pragma unroll
            for (int rf=0;rf<4;rf++){
                int row = rf*16 + lr;
                a[rf] = *(const short8v*)&Al[row*64 + ((jc ^ (row&7))*8)];
            }
            #pragma unroll
            for (int cf=0;cf<4;cf++){
                int row = wave*64 + cf*16 + lr;
                bb[cf] = *(const short8v*)&Bl[row*64 + ((jc ^ (row&7))*8)];
            }
            #pragma unroll
            for (int rf=0;rf<4;rf++)
                #pragma unroll
                for (int cf=0;cf<4;cf++)
                    acc[rf][cf] = __builtin_amdgcn_mfma_f32_16x16x32_bf16(a[rf], bb[cf], acc[rf][cf], 0,0,0);
        }
    }

    float qd[4], ud[4], vd[4];
    #pragma unroll
    for (int cf=0;cf<4;cf++){
        int dcol = wave*64 + cf*16 + lr;
        qd[cf] = Qs[b*DD + dcol];
        ud[cf] = u[dcol];
        vd[cf] = v2[dcol];
    }
    #pragma unroll
    for (int rf=0;rf<4;rf++){
        int rbase = l0 + rf*16 + qw*4;
        float cv[4];
        if (rbase < LL){
            float4 c4v = *(const float4*)(cov + (size_t)b*LL + rbase);
            cv[0]=c4v.x; cv[1]=c4v.y; cv[2]=c4v.z; cv[3]=c4v.w;
        } else { cv[0]=cv[1]=cv[2]=cv[3]=0.f; }
        #pragma unroll
        for (int r=0;r<4;r++){
            float s = 0.f;
            #pragma unroll
            for (int cf=0;cf<4;cf++)
                s += qd[cf] * tanhf(acc[rf][cf][r] + cv[r]*ud[cf] + vd[cf]);
            s += __shfl_xor(s,1); s += __shfl_xor(s,2);
            s += __shfl_xor(s,4); s += __shfl_xor(s,8);
            if (lr == 0) Red[wave][rf*16 + qw*4 + r] = s;
        }
    }
    __syncthreads();
    if (tid < 64){
        int l = l0 + tid;
        if (l < LL){
            float s = Red[0][tid]+Red[1][tid]+Red[2][tid]+Red[3][tid];
            score[b*LL + l] = (pmask[b*LL+l] > 0.f) ? s : -1e18f;
        }
    }
}

// ---------------- softmax over L + coverage copy ------------------------------------
__global__ void k_softmax_l(const float* __restrict__ score, const float* __restrict__ cov_in,
                            float* __restrict__ attn_out, float* __restrict__ cov_out)
{
    const int b = blockIdx.x;
    const int tid = threadIdx.x; // 256
    __shared__ float red[256];
    float m = -INFINITY;
    for (int l=tid;l<LL;l+=256) m = fmaxf(m, score[b*LL+l]);
    red[tid]=m; __syncthreads();
    for (int s=128;s>0;s>>=1){ if(tid<s) red[tid]=fmaxf(red[tid],red[tid+s]); __syncthreads(); }
    m = red[0]; __syncthreads();
    float sum=0.f;
    for (int l=tid;l<LL;l+=256) sum += expf(score[b*LL+l]-m);
    red[tid]=sum; __syncthreads();
    for (int s=128;s>0;s>>=1){ if(tid<s) red[tid]+=red[tid+s]; __syncthreads(); }
    float inv = 1.0f/red[0];
    for (int l=tid;l<LL;l+=256){
        attn_out[b*LL+l] = expf(score[b*LL+l]-m)*inv;
        cov_out[b*LL+l]  = cov_in[b*LL+l];
    }
}

// ---------------- weighted context --------------------------------------------------
#define WCCH 8
__global__ void k_wc(const float* __restrict__ attn, const float* __restrict__ enc,
                     float* __restrict__ wc)
{
    const int b = blockIdx.y, ch = blockIdx.x;
    const int j = threadIdx.x; // 0..511
    const int lc = (LL + WCCH-1)/WCCH;
    const int l0 = ch*lc;
    const int l1 = (l0+lc < LL) ? l0+lc : LL;
    float s = 0.f;
    for (int l=l0;l<l1;l++) s += attn[b*LL+l]*enc[((size_t)(b*LL+l))*2*DD + j];
    atomicAdd(&wc[b*2*DD+j], s);
}

// ============ pregen (+ p_gen in block 0) ==========================================
// grid DD x 256. pregen[b,d] = pre_b[d] + [wc(512), h(256)] . pre_w[d,:]
__global__ __launch_bounds__(256) void k_pregen(
    const float* __restrict__ X, const float* __restrict__ wc,
    const float* __restrict__ o_h, const float* __restrict__ o_c,
    const float* __restrict__ pre_w, const float* __restrict__ pre_b,
    const float* __restrict__ pgen_w, const float* __restrict__ pgen_b,
    float* __restrict__ pregen, float* __restrict__ pgen_out)
{
    const int d = blockIdx.x, t = threadIdx.x;
    const int b = t & 63, w = t >> 6;
    __shared__ float pw[768];
    __shared__ float red[4][64];
    if (t < 192) ((float4*)pw)[t] = ((const float4*)(pre_w + (size_t)d*768))[t];
    __syncthreads();
    const float4* pw4 = (const float4*)pw;
    const float4* wc4 = (const float4*)(wc  + (size_t)b*512);
    const float4* h4  = (const float4*)(o_h + (size_t)b*DD);
    float acc = 0.f;
    for (int i4=w; i4<128; i4+=4)       acc += dot4(wc4[i4],     pw4[i4]);
    for (int i4=128+w; i4<192; i4+=4)   acc += dot4(h4[i4-128],  pw4[i4]);
    red[w][b] = acc; __syncthreads();
    if (t < 64)
        pregen[(size_t)t*DD + d] = pre_b[d] + red[0][t]+red[1][t]+red[2][t]+red[3][t];

    if (blockIdx.x == 0){
        __syncthreads();
        // p_gen[b] = sigmoid([x(256), wc(512), h(256), c(256)] . pgen_w + pgen_b)
        const float4* x4 = (const float4*)(X   + (size_t)b*DD);
        const float4* c4 = (const float4*)(o_c + (size_t)b*DD);
        const float4* pg4 = (const float4*)pgen_w;
        float p = 0.f;
        for (int i4=w; i4<320; i4+=4){
            float4 z;
            if      (i4 < 64)  z = x4[i4];
            else if (i4 < 192) z = wc4[i4-64];
            else if (i4 < 256) z = h4[i4-192];
            else               z = c4[i4-256];
            p += dot4(z, pg4[i4]);
        }
        red[w][b] = p; __syncthreads();
        if (t < 64)
            pgen_out[t] = sigmoidf_(red[0][t]+red[1][t]+red[2][t]+red[3][t] + pgen_b[0]);
    }
}

// ---------------- gen logits: MFMA bf16 ---------------------------------------------
__global__ __launch_bounds__(256) void k_gen_mfma(
    const float* __restrict__ pregen, const float* __restrict__ gen_w,
    const float* __restrict__ gen_b, float* __restrict__ logits, int W)
{
    const int v0 = blockIdx.x * 128;
    const int tid = threadIdx.x;
    const int wave = tid>>6, lane = tid&63, qw = lane>>4, lr = lane&15;

    __shared__ short Al[64*64];
    __shared__ short Bl[128*64];

    f32x4 acc[4][2];
    #pragma unroll
    for (int i=0;i<4;i++){ acc[i][0]=f32x4{0.f,0.f,0.f,0.f}; acc[i][1]=f32x4{0.f,0.f,0.f,0.f}; }

    const int ar = tid>>2, asg = (tid&3)*16;
    const int br = tid>>1, kh = (tid&1)*32;
    const int vrow = v0 + br;

    for (int k0=0;k0<256;k0+=64){
        if (k0) __syncthreads();
        {
            const float4* src = (const float4*)(pregen + ar*DD + k0 + asg);
            short tmp[16];
            #pragma unroll
            for (int i=0;i<4;i++){
                float4 v = src[i];
                tmp[4*i+0]=f2bf(v.x); tmp[4*i+1]=f2bf(v.y);
                tmp[4*i+2]=f2bf(v.z); tmp[4*i+3]=f2bf(v.w);
            }
            const int c0 = asg >> 3;
            #pragma unroll
            for (int i=0;i<2;i++){
                int cc = (c0+i) ^ (ar & 7);
                *(short8v*)&Al[ar*64 + cc*8] = *(const short8v*)&tmp[8*i];
            }
        }
        {
            short tmp[32];
            if (vrow < VV){
                const float4* src = (const float4*)(gen_w + (size_t)vrow*DD + k0 + kh);
                #pragma unroll
                for (int i=0;i<8;i++){
                    float4 v = src[i];
                    tmp[4*i+0]=f2bf(v.x); tmp[4*i+1]=f2bf(v.y);
                    tmp[4*i+2]=f2bf(v.z); tmp[4*i+3]=f2bf(v.w);
                }
            } else {
                #pragma unroll
                for (int i=0;i<32;i++) tmp[i]=0;
            }
            const int c0 = kh >> 3;
            #pragma unroll
            for (int i=0;i<4;i++){
                int cc = (c0+i) ^ (br & 7);
                *(short8v*)&Bl[br*64 + cc*8] = *(const short8v*)&tmp[8*i];
            }
        }
        __syncthreads();

        #pragma unroll
        for (int ks=0; ks<2; ks++){
            const int jc = ks*4 + qw;
            short8v a[4], bb[2];
            #pragma unroll
            for (int rf=0;rf<4;rf++){
                int row = rf*16 + lr;
                a[rf] = *(const short8v*)&Al[row*64 + ((jc ^ (row&7))*8)];
            }
            #pragma unroll
            for (int cf=0;cf<2;cf++){
                int row = wave*32 + cf*16 + lr;
                bb[cf] = *(const short8v*)&Bl[row*64 + ((jc ^ (row&7))*8)];
            }
            #pragma unroll
            for (int rf=0;rf<4;rf++)
                #pragma unroll
                for (int cf=0;cf<2;cf++)
                    acc[rf][cf] = __builtin_amdgcn_mfma_f32_16x16x32_bf16(a[rf], bb[cf], acc[rf][cf], 0,0,0);
        }
    }

    #pragma unroll
    for (int cf=0;cf<2;cf++){
        int v = v0 + wave*32 + cf*16 + lr;
        if (v < VV){
            float gb = gen_b[v];
            #pragma unroll
            for (int rf=0;rf<4;rf++){
                #pragma unroll
                for (int r=0;r<4;r++){
                    int bt = rf*16 + qw*4 + r;
                    logits[(size_t)bt*W + v] = acc[rf][cf][r] + gb;
                }
            }
        }
    }
}

// ---------------- vocab softmax stats -----------------------------------------------
__global__ void k_vsoftmax(const float* __restrict__ logits, float* __restrict__ Ms,
                           float* __restrict__ Ss, int W)
{
    const int b = blockIdx.x;
    const int tid = threadIdx.x; // 1024
    __shared__ float red[1024];
    const float* row = logits + (size_t)b*W;
    float m = -INFINITY;
    for (int v=tid;v<VV;v+=1024) m = fmaxf(m, row[v]);
    red[tid]=m; __syncthreads();
    for (int s=512;s>0;s>>=1){ if(tid<s) red[tid]=fmaxf(red[tid],red[tid+s]); __syncthreads(); }
    m = red[0]; __syncthreads();
    float sum = 0.f;
    for (int v=tid;v<VV;v+=1024) sum += expf(row[v]-m);
    red[tid]=sum; __syncthreads();
    for (int s=512;s>0;s>>=1){ if(tid<s) red[tid]+=red[tid+s]; __syncthreads(); }
    if (tid==0){ Ms[b]=m; Ss[b]=red[0]; }
}

// ---------------- normalize + zero ext ----------------------------------------------
__global__ void k_final(float* __restrict__ out, const float* __restrict__ Ms,
                        const float* __restrict__ Ss, const float* __restrict__ pgen, int W)
{
    size_t idx = (size_t)blockIdx.x*blockDim.x + threadIdx.x;
    if (idx >= (size_t)BB*W) return;
    int b = (int)(idx / W);
    int v = (int)(idx % W);
    float* row = out + (size_t)b*W;
    if (v < VV) row[v] = pgen[b] * expf(row[v]-Ms[b]) / Ss[b];
    else        row[v] = 0.f;
}

// ---------------- scatter-add copy dist ----------------------------------------------
__global__ void k_scatter(float* __restrict__ out, const int* __restrict__ ext,
                          const float* __restrict__ attn, const float* __restrict__ pgen, int W)
{
    int idx = blockIdx.x*blockDim.x + threadIdx.x;
    if (idx >= BB*LL) return;
    int b = idx / LL;
    atomicAdd(out + (size_t)b*W + ext[idx], (1.0f - pgen[b]) * attn[idx]);
}

extern "C" void kernel_launch(void* const* d_in, const int* in_sizes, int n_in,
                              void* d_out, int out_size, void* d_ws, size_t ws_size,
                              hipStream_t stream)
{
    const int*   inp     = (const int*)  d_in[0];
    const float* hh      = (const float*)d_in[1];
    const float* hc      = (const float*)d_in[2];
    const float* enc     = (const float*)d_in[3];
    const float* prev    = (const float*)d_in[4];
    const int*   ext     = (const int*)  d_in[5];
    const float* cov     = (const float*)d_in[6];
    const float* pmask   = (const float*)d_in[7];
    const int*   step_p  = (const int*)  d_in[9];
    const float* emb_w   = (const float*)d_in[10];
    const float* lin_w   = (const float*)d_in[11];
    const float* lin_b   = (const float*)d_in[12];
    const float* w_ih    = (const float*)d_in[13];
    const float* w_hh    = (const float*)d_in[14];
    const float* b_ih    = (const float*)d_in[15];
    const float* b_hh    = (const float*)d_in[16];
    const float* rhw     = (const float*)d_in[17];
    const float* rhb     = (const float*)d_in[18];
    const float* rcw     = (const float*)d_in[19];
    const float* rcb     = (const float*)d_in[20];
    const float* wq_w    = (const float*)d_in[21];
    const float* wq_b    = (const float*)d_in[22];
    const float* cov_w   = (const float*)d_in[23];
    const float* cov_b   = (const float*)d_in[24];
    const float* wk_w    = (const float*)d_in[25];
    const float* wk_b    = (const float*)d_in[26];
    const float* pre_w   = (const float*)d_in[27];
    const float* pre_b   = (const float*)d_in[28];
    const float* gen_w   = (const float*)d_in[29];
    const float* gen_b   = (const float*)d_in[30];
    const float* pgen_w  = (const float*)d_in[31];
    const float* pgen_b  = (const float*)d_in[32];

    const int W = out_size / BB - 4*DD - 2*LL - 1;  // V + ex_size = 50200
    float* out     = (float*)d_out;
    float* o_final = out;
    float* o_h     = out + (size_t)BB*W;
    float* o_c     = o_h + BB*DD;
    float* o_wc    = o_c + BB*DD;
    float* o_attn  = o_wc + BB*2*DD;
    float* o_cov   = o_attn + BB*LL;
    float* o_pgen  = o_cov + BB*LL;

    // workspace
    float* W_x      = (float*)d_ws;          // B*D
    float* W_h      = W_x + BB*DD;           // B*D
    float* W_c      = W_h + BB*DD;           // B*D
    float* W_q      = W_c + BB*DD;           // B*D
    float* W_score  = W_q + BB*DD;           // B*L
    float* W_pregen = W_score + BB*LL;       // B*D
    float* W_m      = W_pregen + BB*DD;      // B
    float* W_s      = W_m + BB;              // B
    float* W_u      = W_s + BB;              // D
    float* W_v2     = W_u + DD;              // D
    short* W_wb     = (short*)(W_v2 + DD);   // D * 2D bf16

    hipMemsetAsync(o_wc, 0, (size_t)BB*2*DD*sizeof(float), stream);

    k_front1<<<dim3(DD,4), 256, 0, stream>>>(inp, hh, hc, prev, emb_w, lin_w, lin_b,
                                             rhw, rhb, rcw, rcb, step_p,
                                             wk_w, wk_b, cov_w, cov_b,
                                             W_x, W_h, W_c, W_wb, W_u, W_v2);
    k_gl<<<DD, 256, 0, stream>>>(W_x, W_h, W_c, w_ih, w_hh, b_ih, b_hh, o_h, o_c);
    k_q2<<<DD, 256, 0, stream>>>(o_h, o_c, wq_w, wq_b, W_q);
    k_score_mfma<<<dim3(7, BB), 256, 0, stream>>>(enc, W_wb, W_u, W_v2, W_q, cov, pmask, W_score);
    k_softmax_l<<<BB, 256, 0, stream>>>(W_score, cov, o_attn, o_cov);
    k_wc<<<dim3(WCCH, BB), 2*DD, 0, stream>>>(o_attn, enc, o_wc);
    k_pregen<<<DD, 256, 0, stream>>>(W_x, o_wc, o_h, o_c, pre_w, pre_b,
                                     pgen_w, pgen_b, W_pregen, o_pgen);
    k_gen_mfma<<<(VV+127)/128, 256, 0, stream>>>(W_pregen, gen_w, gen_b, o_final, W);
    k_vsoftmax<<<BB, 1024, 0, stream>>>(o_final, W_m, W_s, W);
    k_final<<<(int)(((size_t)BB*W+255)/256), 256, 0, stream>>>(o_final, W_m, W_s, o_pgen, W);
    k_scatter<<<(BB*LL+255)/256, 256, 0, stream>>>(o_final, ext, o_attn, o_pgen, W);
}

// Round 4
// 189.071 us; speedup vs baseline: 3.8299x; 1.0523x over previous
//
#include <hip/hip_runtime.h>
#include <math.h>

// V=50000, E=128, D=256, L=400, B=64
#define BB 64
#define DD 256
#define LL 400
#define VV 50000
#define EE 128
#define NB 782   // ceil(VV/64)

typedef __attribute__((ext_vector_type(8))) short short8v;
typedef __attribute__((ext_vector_type(4))) short short4v;
typedef __attribute__((ext_vector_type(4))) float f32x4;

__device__ __forceinline__ float sigmoidf_(float x){ return 1.0f/(1.0f+expf(-x)); }

// fp32 -> bf16 bits, round-to-nearest-even
__device__ __forceinline__ short f2bf(float f){
    unsigned u = __builtin_bit_cast(unsigned, f);
    u += 0x7fffu + ((u>>16)&1u);
    return (short)(u>>16);
}

__device__ __forceinline__ float dot4(float4 a, float4 b){
    return a.x*b.x + a.y*b.y + a.z*b.z + a.w*b.w;
}

// ============ FRONT STAGE 1: x, h, c (+ score prep) ================================
__global__ __launch_bounds__(256) void k_front1(
    const int* __restrict__ inp, const float* __restrict__ hh, const float* __restrict__ hc,
    const float* __restrict__ prev, const float* __restrict__ emb_w,
    const float* __restrict__ lin_w, const float* __restrict__ lin_b,
    const float* __restrict__ rhw, const float* __restrict__ rhb,
    const float* __restrict__ rcw, const float* __restrict__ rcb,
    const int* __restrict__ step_p,
    const float* __restrict__ wk_w, const float* __restrict__ wk_b,
    const float* __restrict__ cov_w, const float* __restrict__ cov_b,
    float* __restrict__ X, float* __restrict__ Wh, float* __restrict__ Wc,
    short* __restrict__ Wb, float* __restrict__ u, float* __restrict__ v2)
{
    const int d = blockIdx.x, y = blockIdx.y, t = threadIdx.x;
    const int b = t & 63, w = t >> 6;
    __shared__ float lw[640];
    __shared__ float red[4][64];

    if (y == 3){
        const float* row = wk_w + (size_t)d*512;
        float su=0.f, sv=0.f;
        for (int j=t; j<512; j+=256){
            float wv = row[j];
            Wb[(size_t)d*512 + j] = f2bf(wv);
            su += wv*cov_w[j];
            sv += wv*cov_b[j];
        }
        float* rs = lw;
        float* rv = &red[0][0];
        rs[t]=su; rv[t]=sv; __syncthreads();
        for (int s=128;s>0;s>>=1){ if(t<s){rs[t]+=rs[t+s]; rv[t]+=rv[t+s];} __syncthreads(); }
        if (t==0){ u[d]=rs[0]; v2[d]=rv[0] + wk_b[d]; }
        return;
    }

    if (y == 0){
        const float4* src4 = (const float4*)(lin_w + (size_t)d*640);
        float4* lw4s = (float4*)lw;
        if (t < 160) lw4s[t] = src4[t];
        __syncthreads();
        const float4* lw4 = (const float4*)lw;
        const float4* er4 = (const float4*)(emb_w + (size_t)inp[b]*EE);
        const float4* pv4 = (const float4*)(prev + (size_t)b*512);
        float acc = 0.f;
        for (int i4=w; i4<32; i4+=4)       acc += dot4(er4[i4],      lw4[i4]);
        for (int i4=32+w; i4<160; i4+=4)   acc += dot4(pv4[i4-32],   lw4[i4]);
        red[w][b] = acc; __syncthreads();
        if (t < 64)
            X[(size_t)t*DD + d] = lin_b[d] + red[0][t]+red[1][t]+red[2][t]+red[3][t];
        return;
    }

    const float* src  = (y==1) ? hh  : hc;
    float*       dst  = (y==1) ? Wh  : Wc;
    if (*step_p == 0){
        const float* wrow = ((y==1) ? rhw : rcw) + (size_t)d*512;
        const float  bias = ((y==1) ? rhb : rcb)[d];
        float4* lw4s = (float4*)lw;
        if (t < 128) lw4s[t] = ((const float4*)wrow)[t];
        __syncthreads();
        const float4* lw4 = (const float4*)lw;
        const float4* s0 = (const float4*)(src + (size_t)b*DD);
        const float4* s1 = (const float4*)(src + (size_t)BB*DD + (size_t)b*DD);
        float acc = 0.f;
        for (int i4=w; i4<64; i4+=4)      acc += dot4(s0[i4],    lw4[i4]);
        for (int i4=64+w; i4<128; i4+=4)  acc += dot4(s1[i4-64], lw4[i4]);
        red[w][b] = acc; __syncthreads();
        if (t < 64){
            float a = bias + red[0][t]+red[1][t]+red[2][t]+red[3][t];
            dst[(size_t)t*DD + d] = a>0.f ? a : 0.f;
        }
    } else {
        if (t < 64) dst[(size_t)t*DD + d] = src[(size_t)t*DD + d];
    }
}

// ============ FRONT STAGE 2: gates + LSTM ==========================================
__global__ __launch_bounds__(256) void k_gl(
    const float* __restrict__ X, const float* __restrict__ Wh, const float* __restrict__ Wc,
    const float* __restrict__ w_ih, const float* __restrict__ w_hh,
    const float* __restrict__ b_ih, const float* __restrict__ b_hh,
    float* __restrict__ o_h, float* __restrict__ o_c)
{
    const int d = blockIdx.x, t = threadIdx.x;
    const int b = t & 63, gi = t >> 6;
    __shared__ float wih[4][256];
    __shared__ float whh[4][256];
    __shared__ float gl[4][64];

    const int gr = gi*DD + d;
    ((float4*)&wih[gi][0])[b] = ((const float4*)(w_ih + (size_t)gr*DD))[b];
    ((float4*)&whh[gi][0])[b] = ((const float4*)(w_hh + (size_t)gr*DD))[b];
    __syncthreads();

    const float4* x4 = (const float4*)(X  + (size_t)b*DD);
    const float4* h4 = (const float4*)(Wh + (size_t)b*DD);
    const float4* wi4 = (const float4*)&wih[gi][0];
    const float4* wh4 = (const float4*)&whh[gi][0];
    float a0=0.f, a1=0.f;
    #pragma unroll 8
    for (int i=0;i<64;i++){
        a0 += dot4(x4[i], wi4[i]);
        a1 += dot4(h4[i], wh4[i]);
    }
    gl[gi][b] = a0 + a1 + b_ih[gr] + b_hh[gr];
    __syncthreads();

    if (t < 64){
        float iv = sigmoidf_(gl[0][t]);
        float fv = sigmoidf_(gl[1][t]);
        float gv = tanhf(gl[2][t]);
        float ov = sigmoidf_(gl[3][t]);
        float cn = fv*Wc[(size_t)t*DD + d] + iv*gv;
        float hn = ov*tanhf(cn);
        o_c[(size_t)t*DD + d] = cn;
        o_h[(size_t)t*DD + d] = hn;
    }
}

// ============ FRONT STAGE 3: Q =====================================================
__global__ __launch_bounds__(256) void k_q2(
    const float* __restrict__ o_h, const float* __restrict__ o_c,
    const float* __restrict__ wq_w, const float* __restrict__ wq_b,
    float* __restrict__ Qs)
{
    const int d = blockIdx.x, t = threadIdx.x;
    const int b = t & 63, w = t >> 6;
    __shared__ float lw[512];
    __shared__ float red[4][64];
    if (t < 128) ((float4*)lw)[t] = ((const float4*)(wq_w + (size_t)d*512))[t];
    __syncthreads();
    const float4* lw4 = (const float4*)lw;
    const float4* h4 = (const float4*)(o_h + (size_t)b*DD);
    const float4* c4 = (const float4*)(o_c + (size_t)b*DD);
    float acc = 0.f;
    for (int i4=w; i4<64; i4+=4)      acc += dot4(h4[i4],    lw4[i4]);
    for (int i4=64+w; i4<128; i4+=4)  acc += dot4(c4[i4-64], lw4[i4]);
    red[w][b] = acc; __syncthreads();
    if (t < 64)
        Qs[(size_t)t*DD + d] = tanhf(wq_b[d] + red[0][t]+red[1][t]+red[2][t]+red[3][t]) * 0.0625f;
}

// ---------------- score: MFMA bf16, 32-row tiles, dbuf LDS, 1 barrier/step ---------
// grid (13, 64), 256 threads. LDS rows padded to 80B (40 shorts) -> conflict-free.
__global__ __launch_bounds__(256) void k_score_mfma(
    const float* __restrict__ enc, const short* __restrict__ Wb,
    const float* __restrict__ u, const float* __restrict__ v2,
    const float* __restrict__ Qs, const float* __restrict__ cov,
    const float* __restrict__ pmask, float* __restrict__ score)
{
    const int b  = blockIdx.y;
    const int l0 = blockIdx.x * 32;
    const int tid = threadIdx.x;
    const int wave = tid >> 6, lane = tid & 63;
    const int qw = lane >> 4, lr = lane & 15;

    __shared__ __align__(16) short As[2][32*40];
    __shared__ __align__(16) short Bs[2][256*40];
    __shared__ float Red[4][32];

    f32x4 acc[2][4];
    #pragma unroll
    for (int i=0;i<2;i++)
        #pragma unroll
        for (int j=0;j<4;j++) acc[i][j] = f32x4{0.f,0.f,0.f,0.f};

    const int arow = tid >> 3;          // 0..31
    const int aseg = (tid & 7) * 4;     // k offset 0..28
    const int al = l0 + arow;
    const bool aval = (al < LL);
    const float* aptr = enc + ((size_t)(b*LL + (aval ? al : 0)))*512 + aseg;
    const short* bptr = Wb + (size_t)tid*512;

    float4 areg;
    short8v breg[4];

    areg = aval ? *(const float4*)aptr : float4{0.f,0.f,0.f,0.f};
    #pragma unroll
    for (int j=0;j<4;j++) breg[j] = *(const short8v*)(bptr + j*8);

    int cur = 0;
    for (int step=0; step<16; ++step){
        {
            short4v t4;
            t4[0]=f2bf(areg.x); t4[1]=f2bf(areg.y); t4[2]=f2bf(areg.z); t4[3]=f2bf(areg.w);
            *(short4v*)&As[cur][arow*40 + aseg] = t4;
            #pragma unroll
            for (int j=0;j<4;j++)
                *(short8v*)&Bs[cur][tid*40 + j*8] = breg[j];
        }
        if (step < 15){
            const int k0 = (step+1)*32;
            areg = aval ? *(const float4*)(aptr + k0) : float4{0.f,0.f,0.f,0.f};
            #pragma unroll
            for (int j=0;j<4;j++) breg[j] = *(const short8v*)(bptr + k0 + j*8);
        }
        __syncthreads();
        short8v a[2], bb[4];
        #pragma unroll
        for (int rf=0;rf<2;rf++)
            a[rf] = *(const short8v*)&As[cur][(rf*16+lr)*40 + qw*8];
        #pragma unroll
        for (int cf=0;cf<4;cf++)
            bb[cf] = *(const short8v*)&Bs[cur][(wave*64+cf*16+lr)*40 + qw*8];
        #pragma unroll
        for (int rf=0;rf<2;rf++)
            #pragma unroll
            for (int cf=0;cf<4;cf++)
                acc[rf][cf] = __builtin_amdgcn_mfma_f32_16x16x32_bf16(a[rf], bb[cf], acc[rf][cf], 0,0,0);
        cur ^= 1;
    }

    // epilogue: tanh + Qs dot + row reduce
    float qd[4], ud[4], vd[4];
    #pragma unroll
    for (int cf=0;cf<4;cf++){
        int dcol = wave*64 + cf*16 + lr;
        qd[cf] = Qs[b*DD + dcol];
        ud[cf] = u[dcol];
        vd[cf] = v2[dcol];
    }
    #pragma unroll
    for (int rf=0;rf<2;rf++){
        int rbase = l0 + rf*16 + qw*4;
        float cv[4];
        if (rbase < LL){
            float4 c4v = *(const float4*)(cov + (size_t)b*LL + rbase);
            cv[0]=c4v.x; cv[1]=c4v.y; cv[2]=c4v.z; cv[3]=c4v.w;
        } else { cv[0]=cv[1]=cv[2]=cv[3]=0.f; }
        #pragma unroll
        for (int r=0;r<4;r++){
            float s = 0.f;
            #pragma unroll
            for (int cf=0;cf<4;cf++)
                s += qd[cf] * tanhf(acc[rf][cf][r] + cv[r]*ud[cf] + vd[cf]);
            s += __shfl_xor(s,1); s += __shfl_xor(s,2);
            s += __shfl_xor(s,4); s += __shfl_xor(s,8);
            if (lr == 0) Red[wave][rf*16 + qw*4 + r] = s;
        }
    }
    __syncthreads();
    if (tid < 32){
        int l = l0 + tid;
        if (l < LL){
            float s = Red[0][tid]+Red[1][tid]+Red[2][tid]+Red[3][tid];
            score[b*LL + l] = (pmask[b*LL+l] > 0.f) ? s : -1e18f;
        }
    }
}

// ---------------- fused softmax(L) + weighted context + attn/cov out ---------------
// grid (8, 64), 512 threads. Each block recomputes the cheap row softmax.
__global__ __launch_bounds__(512) void k_wcsm(
    const float* __restrict__ score, const float* __restrict__ cov_in,
    const float* __restrict__ enc,
    float* __restrict__ attn_out, float* __restrict__ cov_out, float* __restrict__ wc)
{
    const int b = blockIdx.y, ch = blockIdx.x;
    const int t = threadIdx.x;
    __shared__ float sc[LL];
    __shared__ float red[512];

    float v = (t < LL) ? score[b*LL + t] : -INFINITY;
    red[t] = v; __syncthreads();
    for (int s=256;s>0;s>>=1){ if(t<s) red[t]=fmaxf(red[t],red[t+s]); __syncthreads(); }
    float m = red[0]; __syncthreads();
    float e = (t < LL) ? expf(v - m) : 0.f;
    if (t < LL) sc[t] = e;
    red[t] = e; __syncthreads();
    for (int s=256;s>0;s>>=1){ if(t<s) red[t]+=red[t+s]; __syncthreads(); }
    const float inv = 1.0f / red[0];

    const int l0 = ch * (LL/8);
    float s = 0.f;
    #pragma unroll 5
    for (int l=l0; l<l0+LL/8; ++l)
        s += sc[l] * enc[((size_t)(b*LL+l))*512 + t];
    atomicAdd(&wc[b*512 + t], s * inv);

    if (ch == 0 && t < LL){
        attn_out[b*LL + t] = sc[t] * inv;
        cov_out[b*LL + t]  = cov_in[b*LL + t];
    }
}

// ============ pregen (+ p_gen in block 0) ==========================================
__global__ __launch_bounds__(256) void k_pregen(
    const float* __restrict__ X, const float* __restrict__ wc,
    const float* __restrict__ o_h, const float* __restrict__ o_c,
    const float* __restrict__ pre_w, const float* __restrict__ pre_b,
    const float* __restrict__ pgen_w, const float* __restrict__ pgen_b,
    float* __restrict__ pregen, float* __restrict__ pgen_out)
{
    const int d = blockIdx.x, t = threadIdx.x;
    const int b = t & 63, w = t >> 6;
    __shared__ float pw[768];
    __shared__ float red[4][64];
    if (t < 192) ((float4*)pw)[t] = ((const float4*)(pre_w + (size_t)d*768))[t];
    __syncthreads();
    const float4* pw4 = (const float4*)pw;
    const float4* wc4 = (const float4*)(wc  + (size_t)b*512);
    const float4* h4  = (const float4*)(o_h + (size_t)b*DD);
    float acc = 0.f;
    for (int i4=w; i4<128; i4+=4)       acc += dot4(wc4[i4],     pw4[i4]);
    for (int i4=128+w; i4<192; i4+=4)   acc += dot4(h4[i4-128],  pw4[i4]);
    red[w][b] = acc; __syncthreads();
    if (t < 64)
        pregen[(size_t)t*DD + d] = pre_b[d] + red[0][t]+red[1][t]+red[2][t]+red[3][t];

    if (blockIdx.x == 0){
        __syncthreads();
        const float4* x4 = (const float4*)(X   + (size_t)b*DD);
        const float4* c4 = (const float4*)(o_c + (size_t)b*DD);
        const float4* pg4 = (const float4*)pgen_w;
        float p = 0.f;
        for (int i4=w; i4<320; i4+=4){
            float4 z;
            if      (i4 < 64)  z = x4[i4];
            else if (i4 < 192) z = wc4[i4-64];
            else if (i4 < 256) z = h4[i4-192];
            else               z = c4[i4-256];
            p += dot4(z, pg4[i4]);
        }
        red[w][b] = p; __syncthreads();
        if (t < 64)
            pgen_out[t] = sigmoidf_(red[0][t]+red[1][t]+red[2][t]+red[3][t] + pgen_b[0]);
    }
}

// ---------------- gen logits: MFMA bf16, 64-v tiles, dbuf, fused softmax partials ---
__global__ __launch_bounds__(256) void k_gen_mfma(
    const float* __restrict__ pregen, const float* __restrict__ gen_w,
    const float* __restrict__ gen_b, float* __restrict__ logits,
    float* __restrict__ blkM, float* __restrict__ blkS, int W)
{
    const int blk = blockIdx.x;
    const int v0 = blk * 64;
    const int tid = threadIdx.x;
    const int wave = tid>>6, lane = tid&63, qw = lane>>4, lr = lane&15;

    __shared__ __align__(16) short Ag[2][64*40];
    __shared__ __align__(16) short Bg[2][64*40];
    __shared__ float pm[4][64];
    __shared__ float ps[4][64];

    f32x4 acc[4];
    #pragma unroll
    for (int i=0;i<4;i++) acc[i] = f32x4{0.f,0.f,0.f,0.f};

    const int arow = tid >> 2;          // 0..63
    const int aseg = (tid & 3) * 8;     // 0,8,16,24
    const float* aptr = pregen + (size_t)arow*DD + aseg;
    const int vrow = v0 + arow;
    const bool bval = (vrow < VV);
    const float* bptr = gen_w + (size_t)(bval ? vrow : 0)*DD + aseg;

    float4 ar0, ar1, br0, br1;
    ar0 = ((const float4*)aptr)[0]; ar1 = ((const float4*)aptr)[1];
    if (bval){ br0 = ((const float4*)bptr)[0]; br1 = ((const float4*)bptr)[1]; }
    else { br0 = float4{0.f,0.f,0.f,0.f}; br1 = br0; }

    int cur = 0;
    for (int step=0; step<8; ++step){
        {
            short8v t8;
            t8[0]=f2bf(ar0.x); t8[1]=f2bf(ar0.y); t8[2]=f2bf(ar0.z); t8[3]=f2bf(ar0.w);
            t8[4]=f2bf(ar1.x); t8[5]=f2bf(ar1.y); t8[6]=f2bf(ar1.z); t8[7]=f2bf(ar1.w);
            *(short8v*)&Ag[cur][arow*40 + aseg] = t8;
            t8[0]=f2bf(br0.x); t8[1]=f2bf(br0.y); t8[2]=f2bf(br0.z); t8[3]=f2bf(br0.w);
            t8[4]=f2bf(br1.x); t8[5]=f2bf(br1.y); t8[6]=f2bf(br1.z); t8[7]=f2bf(br1.w);
            *(short8v*)&Bg[cur][arow*40 + aseg] = t8;
        }
        if (step < 7){
            const int k0 = (step+1)*32;
            ar0 = ((const float4*)(aptr + k0))[0]; ar1 = ((const float4*)(aptr + k0))[1];
            if (bval){ br0 = ((const float4*)(bptr + k0))[0]; br1 = ((const float4*)(bptr + k0))[1]; }
        }
        __syncthreads();
        short8v a[4], bb;
        #pragma unroll
        for (int rf=0;rf<4;rf++)
            a[rf] = *(const short8v*)&Ag[cur][(rf*16+lr)*40 + qw*8];
        bb = *(const short8v*)&Bg[cur][(wave*16+lr)*40 + qw*8];
        #pragma unroll
        for (int rf=0;rf<4;rf++)
            acc[rf] = __builtin_amdgcn_mfma_f32_16x16x32_bf16(a[rf], bb, acc[rf], 0,0,0);
        cur ^= 1;
    }

    // epilogue: logits write + per-block softmax partials
    const int v = v0 + wave*16 + lr;
    const bool vv = (v < VV);
    const float gb = vv ? gen_b[v] : 0.f;
    #pragma unroll
    for (int rf=0;rf<4;rf++){
        #pragma unroll
        for (int r=0;r<4;r++){
            float lg = acc[rf][r] + gb;
            int bt = rf*16 + qw*4 + r;
            if (vv) logits[(size_t)bt*W + v] = lg;
            float x = vv ? lg : -1e30f;
            float mx = x;
            mx = fmaxf(mx, __shfl_xor(mx,1));
            mx = fmaxf(mx, __shfl_xor(mx,2));
            mx = fmaxf(mx, __shfl_xor(mx,4));
            mx = fmaxf(mx, __shfl_xor(mx,8));
            float e = vv ? expf(x - mx) : 0.f;
            e += __shfl_xor(e,1); e += __shfl_xor(e,2);
            e += __shfl_xor(e,4); e += __shfl_xor(e,8);
            if (lr == 0){ pm[wave][bt] = mx; ps[wave][bt] = e; }
        }
    }
    __syncthreads();
    if (tid < 64){
        float M = fmaxf(fmaxf(pm[0][tid], pm[1][tid]), fmaxf(pm[2][tid], pm[3][tid]));
        float S = ps[0][tid]*expf(pm[0][tid]-M) + ps[1][tid]*expf(pm[1][tid]-M)
                + ps[2][tid]*expf(pm[2][tid]-M) + ps[3][tid]*expf(pm[3][tid]-M);
        blkM[(size_t)tid*NB + blk] = M;
        blkS[(size_t)tid*NB + blk] = S;
    }
}

// ---------------- reduce per-block partials -> M,S per batch -----------------------
__global__ __launch_bounds__(256) void k_vred(
    const float* __restrict__ blkM, const float* __restrict__ blkS,
    float* __restrict__ Ms, float* __restrict__ Ss)
{
    const int b = blockIdx.x, t = threadIdx.x;
    __shared__ float red[256];
    float m = -INFINITY;
    for (int i=t; i<NB; i+=256) m = fmaxf(m, blkM[(size_t)b*NB + i]);
    red[t]=m; __syncthreads();
    for (int s=128;s>0;s>>=1){ if(t<s) red[t]=fmaxf(red[t],red[t+s]); __syncthreads(); }
    const float M = red[0]; __syncthreads();
    float s = 0.f;
    for (int i=t; i<NB; i+=256) s += blkS[(size_t)b*NB + i] * expf(blkM[(size_t)b*NB + i] - M);
    red[t]=s; __syncthreads();
    for (int st=128;st>0;st>>=1){ if(t<st) red[t]+=red[t+st]; __syncthreads(); }
    if (t==0){ Ms[b]=M; Ss[b]=red[0]; }
}

// ---------------- normalize + zero ext ----------------------------------------------
__global__ void k_final(float* __restrict__ out, const float* __restrict__ Ms,
                        const float* __restrict__ Ss, const float* __restrict__ pgen, int W)
{
    size_t idx = (size_t)blockIdx.x*blockDim.x + threadIdx.x;
    if (idx >= (size_t)BB*W) return;
    int b = (int)(idx / W);
    int v = (int)(idx % W);
    float* row = out + (size_t)b*W;
    if (v < VV) row[v] = pgen[b] * expf(row[v]-Ms[b]) / Ss[b];
    else        row[v] = 0.f;
}

// ---------------- scatter-add copy dist ----------------------------------------------
__global__ void k_scatter(float* __restrict__ out, const int* __restrict__ ext,
                          const float* __restrict__ attn, const float* __restrict__ pgen, int W)
{
    int idx = blockIdx.x*blockDim.x + threadIdx.x;
    if (idx >= BB*LL) return;
    int b = idx / LL;
    atomicAdd(out + (size_t)b*W + ext[idx], (1.0f - pgen[b]) * attn[idx]);
}

extern "C" void kernel_launch(void* const* d_in, const int* in_sizes, int n_in,
                              void* d_out, int out_size, void* d_ws, size_t ws_size,
                              hipStream_t stream)
{
    const int*   inp     = (const int*)  d_in[0];
    const float* hh      = (const float*)d_in[1];
    const float* hc      = (const float*)d_in[2];
    const float* enc     = (const float*)d_in[3];
    const float* prev    = (const float*)d_in[4];
    const int*   ext     = (const int*)  d_in[5];
    const float* cov     = (const float*)d_in[6];
    const float* pmask   = (const float*)d_in[7];
    const int*   step_p  = (const int*)  d_in[9];
    const float* emb_w   = (const float*)d_in[10];
    const float* lin_w   = (const float*)d_in[11];
    const float* lin_b   = (const float*)d_in[12];
    const float* w_ih    = (const float*)d_in[13];
    const float* w_hh    = (const float*)d_in[14];
    const float* b_ih    = (const float*)d_in[15];
    const float* b_hh    = (const float*)d_in[16];
    const float* rhw     = (const float*)d_in[17];
    const float* rhb     = (const float*)d_in[18];
    const float* rcw     = (const float*)d_in[19];
    const float* rcb     = (const float*)d_in[20];
    const float* wq_w    = (const float*)d_in[21];
    const float* wq_b    = (const float*)d_in[22];
    const float* cov_w   = (const float*)d_in[23];
    const float* cov_b   = (const float*)d_in[24];
    const float* wk_w    = (const float*)d_in[25];
    const float* wk_b    = (const float*)d_in[26];
    const float* pre_w   = (const float*)d_in[27];
    const float* pre_b   = (const float*)d_in[28];
    const float* gen_w   = (const float*)d_in[29];
    const float* gen_b   = (const float*)d_in[30];
    const float* pgen_w  = (const float*)d_in[31];
    const float* pgen_b  = (const float*)d_in[32];

    const int W = out_size / BB - 4*DD - 2*LL - 1;  // V + ex_size = 50200
    float* out     = (float*)d_out;
    float* o_final = out;
    float* o_h     = out + (size_t)BB*W;
    float* o_c     = o_h + BB*DD;
    float* o_wc    = o_c + BB*DD;
    float* o_attn  = o_wc + BB*2*DD;
    float* o_cov   = o_attn + BB*LL;
    float* o_pgen  = o_cov + BB*LL;

    // workspace
    float* W_x      = (float*)d_ws;          // B*D
    float* W_h      = W_x + BB*DD;           // B*D
    float* W_c      = W_h + BB*DD;           // B*D
    float* W_q      = W_c + BB*DD;           // B*D
    float* W_score  = W_q + BB*DD;           // B*L
    float* W_pregen = W_score + BB*LL;       // B*D
    float* W_m      = W_pregen + BB*DD;      // B
    float* W_s      = W_m + BB;              // B
    float* W_u      = W_s + BB;              // D
    float* W_v2     = W_u + DD;              // D
    float* W_blkM   = W_v2 + DD;             // B*NB
    float* W_blkS   = W_blkM + (size_t)BB*NB;          // B*NB
    short* W_wb     = (short*)(W_blkS + (size_t)BB*NB); // D*2D bf16

    hipMemsetAsync(o_wc, 0, (size_t)BB*2*DD*sizeof(float), stream);

    k_front1<<<dim3(DD,4), 256, 0, stream>>>(inp, hh, hc, prev, emb_w, lin_w, lin_b,
                                             rhw, rhb, rcw, rcb, step_p,
                                             wk_w, wk_b, cov_w, cov_b,
                                             W_x, W_h, W_c, W_wb, W_u, W_v2);
    k_gl<<<DD, 256, 0, stream>>>(W_x, W_h, W_c, w_ih, w_hh, b_ih, b_hh, o_h, o_c);
    k_q2<<<DD, 256, 0, stream>>>(o_h, o_c, wq_w, wq_b, W_q);
    k_score_mfma<<<dim3(13, BB), 256, 0, stream>>>(enc, W_wb, W_u, W_v2, W_q, cov, pmask, W_score);
    k_wcsm<<<dim3(8, BB), 512, 0, stream>>>(W_score, cov, enc, o_attn, o_cov, o_wc);
    k_pregen<<<DD, 256, 0, stream>>>(W_x, o_wc, o_h, o_c, pre_w, pre_b,
                                     pgen_w, pgen_b, W_pregen, o_pgen);
    k_gen_mfma<<<NB, 256, 0, stream>>>(W_pregen, gen_w, gen_b, o_final, W_blkM, W_blkS, W);
    k_vred<<<BB, 256, 0, stream>>>(W_blkM, W_blkS, W_m, W_s);
    k_final<<<(int)(((size_t)BB*W+255)/256), 256, 0, stream>>>(o_final, W_m, W_s, o_pgen, W);
    k_scatter<<<(BB*LL+255)/256, 256, 0, stream>>>(o_final, ext, o_attn, o_pgen, W);
}